// Round 5
// baseline (883.073 us; speedup 1.0000x reference)
//
#include <hip/hip_runtime.h>
#include <math.h>

typedef unsigned short u16;
typedef unsigned int u32;
typedef __attribute__((ext_vector_type(8))) short bf16x8;
typedef __attribute__((ext_vector_type(4))) float f32x4;
typedef __attribute__((ext_vector_type(4))) u16 u16x4;

__device__ __forceinline__ u16 f2bf(float f) {
  u32 u = __builtin_bit_cast(u32, f);
  u32 r = (u + 0x7fffu + ((u >> 16) & 1u)) >> 16;
  return (u16)r;
}

__device__ __forceinline__ void async16(const void* g, void* l) {
  __builtin_amdgcn_global_load_lds(
      (__attribute__((address_space(1))) void*)(unsigned long long)(const char*)g,
      (__attribute__((address_space(3))) void*)l, 16, 0, 0);
}

#define SCHED0 __builtin_amdgcn_sched_barrier(0)
#define BARRIER __builtin_amdgcn_s_barrier()

// ---------------------------------------------------------------------------
// Weight f32 -> bf16 conversion (10 segments, one launch)
// ---------------------------------------------------------------------------
struct Conv10 {
  const float* src[10];
  u16* dst[10];
  int n[10];
};

__global__ __launch_bounds__(256) void convert10(Conv10 a) {
  const int seg = blockIdx.y;
  const long i = ((long)blockIdx.x * 256 + threadIdx.x) * 4;
  if (i >= a.n[seg]) return;
  float4 v = *(const float4*)&a.src[seg][i];
  u16x4 o;
  o.x = f2bf(v.x); o.y = f2bf(v.y); o.z = f2bf(v.z); o.w = f2bf(v.w);
  *(u16x4*)&a.dst[seg][i] = o;
}

// ---------------------------------------------------------------------------
// LayerNorm (two tensors fused in one launch), f32 in -> bf16 out, 1 wave/row
// ---------------------------------------------------------------------------
__global__ __launch_bounds__(256) void ln_dual(
    const float* __restrict__ in1, const float* __restrict__ g1, const float* __restrict__ b1,
    u16* __restrict__ out1, int rows1,
    const float* __restrict__ in2, const float* __restrict__ g2, const float* __restrict__ b2,
    u16* __restrict__ out2)
{
  const int w = threadIdx.x >> 6;
  const int lane = threadIdx.x & 63;
  const int row = blockIdx.x * 4 + w;
  const float* in; const float* gg; const float* bb; u16* out;
  if (row < rows1) { in = in1 + (size_t)row * 768; gg = g1; bb = b1; out = out1 + (size_t)row * 768; }
  else { const int r2 = row - rows1; in = in2 + (size_t)r2 * 768; gg = g2; bb = b2; out = out2 + (size_t)r2 * 768; }

  float4 v0 = *(const float4*)&in[lane * 4];
  float4 v1 = *(const float4*)&in[lane * 4 + 256];
  float4 v2 = *(const float4*)&in[lane * 4 + 512];
  float s = v0.x + v0.y + v0.z + v0.w + v1.x + v1.y + v1.z + v1.w + v2.x + v2.y + v2.z + v2.w;
  float s2 = v0.x*v0.x + v0.y*v0.y + v0.z*v0.z + v0.w*v0.w
           + v1.x*v1.x + v1.y*v1.y + v1.z*v1.z + v1.w*v1.w
           + v2.x*v2.x + v2.y*v2.y + v2.z*v2.z + v2.w*v2.w;
#pragma unroll
  for (int m = 1; m <= 32; m <<= 1) { s += __shfl_xor(s, m); s2 += __shfl_xor(s2, m); }
  const float mean = s * (1.0f / 768.0f);
  const float var = s2 * (1.0f / 768.0f) - mean * mean;
  const float rs = rsqrtf(var + 1e-5f);

#define LNSTORE(V, OFFS) { \
    float4 gv = *(const float4*)&gg[lane * 4 + OFFS]; \
    float4 bv = *(const float4*)&bb[lane * 4 + OFFS]; \
    u16x4 o; \
    o.x = f2bf((V.x - mean) * rs * gv.x + bv.x); \
    o.y = f2bf((V.y - mean) * rs * gv.y + bv.y); \
    o.z = f2bf((V.z - mean) * rs * gv.z + bv.z); \
    o.w = f2bf((V.w - mean) * rs * gv.w + bv.w); \
    *(u16x4*)&out[lane * 4 + OFFS] = o; }
  LNSTORE(v0, 0)
  LNSTORE(v1, 256)
  LNSTORE(v2, 512)
#undef LNSTORE
}

// ---------------------------------------------------------------------------
// gemm_bt: round-1 kernel (m97 structure), kept for small z-side GEMMs.
// ---------------------------------------------------------------------------
template<int EPI>
__global__ __launch_bounds__(256) void gemm_bt(
    const u16* __restrict__ A, const u16* __restrict__ W,
    const float* __restrict__ bias, const float* __restrict__ res,
    void* __restrict__ outp, int M, int N, int K)
{
  __shared__ __align__(16) u16 As[128 * 32];
  __shared__ __align__(16) u16 Bs[128 * 32];
  const int tid = threadIdx.x;
  const int lane = tid & 63;
  const int w = tid >> 6;
  const long row0 = (long)blockIdx.y * 128;
  const long col0 = (long)blockIdx.x * 128;

  const int lr0 = w * 32 + (lane >> 2);
  const int lr1 = lr0 + 16;
  const int sl = lane & 3;
  const int ss0 = sl ^ ((lr0 >> 1) & 3);
  const int ss1 = sl ^ ((lr1 >> 1) & 3);
  const u16* ga0 = A + (row0 + lr0) * (long)K + ss0 * 8;
  const u16* ga1 = A + (row0 + lr1) * (long)K + ss1 * 8;
  const u16* gb0 = W + (col0 + lr0) * (long)K + ss0 * 8;
  const u16* gb1 = W + (col0 + lr1) * (long)K + ss1 * 8;
  u16* la0 = &As[(w * 2 + 0) * 512];
  u16* la1 = &As[(w * 2 + 1) * 512];
  u16* lb0 = &Bs[(w * 2 + 0) * 512];
  u16* lb1 = &Bs[(w * 2 + 1) * 512];

  const int fr = lane & 15;
  const int g = lane >> 4;
  const int wr = (w >> 1) * 64;
  const int wc = (w & 1) * 64;

  f32x4 acc[4][4];
#pragma unroll
  for (int m = 0; m < 4; ++m)
#pragma unroll
    for (int n = 0; n < 4; ++n) acc[m][n] = (f32x4){0.f, 0.f, 0.f, 0.f};

  for (int k0 = 0; k0 < K; k0 += 32) {
    async16(ga0, la0); async16(ga1, la1);
    async16(gb0, lb0); async16(gb1, lb1);
    ga0 += 32; ga1 += 32; gb0 += 32; gb1 += 32;
    __syncthreads();
    bf16x8 af[4], bfr[4];
#pragma unroll
    for (int m = 0; m < 4; ++m) {
      const int r = wr + m * 16 + fr;
      af[m] = *(const bf16x8*)&As[r * 32 + ((g ^ ((r >> 1) & 3)) * 8)];
    }
#pragma unroll
    for (int n = 0; n < 4; ++n) {
      const int r = wc + n * 16 + fr;
      bfr[n] = *(const bf16x8*)&Bs[r * 32 + ((g ^ ((r >> 1) & 3)) * 8)];
    }
#pragma unroll
    for (int m = 0; m < 4; ++m)
#pragma unroll
      for (int n = 0; n < 4; ++n)
        acc[m][n] = __builtin_amdgcn_mfma_f32_16x16x32_bf16(af[m], bfr[n], acc[m][n], 0, 0, 0);
    __syncthreads();
  }

#pragma unroll
  for (int n = 0; n < 4; ++n) {
    const long col = col0 + wc + n * 16 + fr;
    const float bv = bias[col];
#pragma unroll
    for (int m = 0; m < 4; ++m) {
#pragma unroll
      for (int j = 0; j < 4; ++j) {
        const long row = row0 + wr + m * 16 + g * 4 + j;
        const long off = row * N + col;
        float v = acc[m][n][j] + bv;
        if constexpr (EPI == 0) {
          ((u16*)outp)[off] = f2bf(v);
        } else if constexpr (EPI == 1) {
          float ge = 0.5f * v * (1.0f + erff(v * 0.70710678118654752f));
          ((u16*)outp)[off] = f2bf(ge);
        } else {
          ((float*)outp)[off] = v + res[off];
        }
      }
    }
  }
}

// ---------------------------------------------------------------------------
// gemm8: 8-phase counted-vmcnt 256x256 GEMM (m201-style, K-split halves).
// BK=64 split into 2 k-halves of 32; LDS As/Bs[2 buf][2 kh][256*32] = 128 KB.
// Per K-tile, 4 phases (mh,kh) = (0,0),(1,0),(0,1),(1,1):
//   {ds_read 4-8 b128 | stage 1 chunk (2 gload_lds)} -> barrier ->
//   lgkmcnt(0) -> setprio(1) -> 16 MFMA -> setprio(0) -> [odd: vmcnt gate]
//   -> barrier.
// Stage schedule (phase p, T=p>>2): q0: A-kh1(T+1), q1: B-kh1(T+1),
// q2: A-kh0(T+2), q3: B-kh0(T+2). Chunk age at first read = 5-6 phases.
// Gates: vmcnt(8) steady (12 in flight, wait oldest 4); tail: vmcnt(4)
// at (nt-2).q3, vmcnt(0) at (nt-1).q1. WAR safety: dual barrier +
// lgkmcnt(0) retires all reads of a region before any wave can issue the
// stage that overwrites it.  Swizzle: slot ^ ((row>>1)&3) (2-way, free),
// pre-applied on the global source; linear gload_lds dest.
// ---------------------------------------------------------------------------
template<int EPI>
__global__ __launch_bounds__(512, 2) void gemm8(
    const u16* __restrict__ A, const u16* __restrict__ W,
    const float* __restrict__ bias, const float* __restrict__ res,
    void* __restrict__ outp, int M, int N, int K)
{
  __shared__ __align__(16) u16 As[2][2][8192];
  __shared__ __align__(16) u16 Bs[2][2][8192];

  const int tid = threadIdx.x;
  const int lane = tid & 63;
  const int w = tid >> 6;
  const int wm = w >> 2;   // 0..1
  const int wn = w & 3;    // 0..3

  int flat = blockIdx.y * gridDim.x + blockIdx.x;
  const int nwg = gridDim.x * gridDim.y;
  if ((nwg & 7) == 0) flat = (flat & 7) * (nwg >> 3) + (flat >> 3);
  const int bx = flat % gridDim.x;
  const int by = flat / gridDim.x;
  const long row0 = (long)by * 256;
  const long col0 = (long)bx * 256;

  // staging: chunk = one matrix x one k-half = 256 rows x 32 k = 1024 x 8elem
  const int c0 = tid, c1 = tid + 512;
  const int r0 = c0 >> 2, r1 = c1 >> 2;
  const long ks0 = ((c0 & 3) ^ ((r0 >> 1) & 3)) * 8;
  const long ks1 = ((c1 & 3) ^ ((r1 >> 1) & 3)) * 8;
  const u16* gA0 = A + (row0 + r0) * (long)K + ks0;
  const u16* gA1 = A + (row0 + r1) * (long)K + ks1;
  const u16* gB0 = W + (col0 + r0) * (long)K + ks0;
  const u16* gB1 = W + (col0 + r1) * (long)K + ks1;

  const int fr = lane & 15;
  const int g = lane >> 4;
  const int sl = (g ^ ((fr >> 1) & 3)) * 8;

  int aoff[8], boff[4];
#pragma unroll
  for (int m = 0; m < 8; ++m) aoff[m] = (wm * 128 + m * 16 + fr) * 32 + sl;
#pragma unroll
  for (int n = 0; n < 4; ++n) boff[n] = (wn * 64 + n * 16 + fr) * 32 + sl;

  f32x4 acc[8][4];
#pragma unroll
  for (int m = 0; m < 8; ++m)
#pragma unroll
    for (int n = 0; n < 4; ++n) acc[m][n] = (f32x4){0.f, 0.f, 0.f, 0.f};

  auto stgA = [&](int buf, int kh, int t) {
    const long ko = (long)t * 64 + kh * 32;
    async16(gA0 + ko, &As[buf][kh][c0 * 8]);
    async16(gA1 + ko, &As[buf][kh][c1 * 8]);
  };
  auto stgB = [&](int buf, int kh, int t) {
    const long ko = (long)t * 64 + kh * 32;
    async16(gB0 + ko, &Bs[buf][kh][c0 * 8]);
    async16(gB1 + ko, &Bs[buf][kh][c1 * 8]);
  };

  const int nt = K / 64;

  // prologue: kh0(0), kh1(0), kh0(1) -- 12 loads; keep 8 in flight
  stgA(0, 0, 0); stgB(0, 0, 0);
  stgA(0, 1, 0); stgB(0, 1, 0);
  stgA(1, 0, 1); stgB(1, 0, 1);
  asm volatile("s_waitcnt vmcnt(8)" ::: "memory");
  BARRIER;
  SCHED0;

  for (int t = 0; t < nt; ++t) {
    const int buf = t & 1, nb = (t + 1) & 1;
    const u16* A0 = As[buf][0];
    const u16* A1 = As[buf][1];
    const u16* B0 = Bs[buf][0];
    const u16* B1 = Bs[buf][1];
    const bool st1 = (t + 1 < nt), st2 = (t + 2 < nt);
    bf16x8 bfr[4], af[4];

#define PHASE_MFMA(MBASE)                                                     \
    __builtin_amdgcn_s_setprio(1);                                            \
    _Pragma("unroll")                                                         \
    for (int m = 0; m < 4; ++m)                                               \
      _Pragma("unroll")                                                       \
      for (int n = 0; n < 4; ++n)                                             \
        acc[MBASE + m][n] =                                                   \
          __builtin_amdgcn_mfma_f32_16x16x32_bf16(af[m], bfr[n],              \
                                                  acc[MBASE + m][n], 0, 0, 0);\
    __builtin_amdgcn_s_setprio(0);

    // ---- q0: (mh0, kh0)
#pragma unroll
    for (int n = 0; n < 4; ++n) bfr[n] = *(const bf16x8*)&B0[boff[n]];
#pragma unroll
    for (int m = 0; m < 4; ++m) af[m] = *(const bf16x8*)&A0[aoff[m]];
    if (st1) stgA(nb, 1, t + 1);
    SCHED0; BARRIER;
    asm volatile("s_waitcnt lgkmcnt(0)" ::: "memory");
    SCHED0;
    PHASE_MFMA(0)
    SCHED0; BARRIER; SCHED0;

    // ---- q1: (mh1, kh0)
#pragma unroll
    for (int m = 0; m < 4; ++m) af[m] = *(const bf16x8*)&A0[aoff[m + 4]];
    if (st1) stgB(nb, 1, t + 1);
    SCHED0; BARRIER;
    asm volatile("s_waitcnt lgkmcnt(0)" ::: "memory");
    SCHED0;
    PHASE_MFMA(4)
    SCHED0;
    if (t == nt - 1) { asm volatile("s_waitcnt vmcnt(0)" ::: "memory"); }
    else             { asm volatile("s_waitcnt vmcnt(8)" ::: "memory"); }
    BARRIER; SCHED0;

    // ---- q2: (mh0, kh1)
#pragma unroll
    for (int n = 0; n < 4; ++n) bfr[n] = *(const bf16x8*)&B1[boff[n]];
#pragma unroll
    for (int m = 0; m < 4; ++m) af[m] = *(const bf16x8*)&A1[aoff[m]];
    if (st2) stgA(buf, 0, t + 2);
    SCHED0; BARRIER;
    asm volatile("s_waitcnt lgkmcnt(0)" ::: "memory");
    SCHED0;
    PHASE_MFMA(0)
    SCHED0; BARRIER; SCHED0;

    // ---- q3: (mh1, kh1)
#pragma unroll
    for (int m = 0; m < 4; ++m) af[m] = *(const bf16x8*)&A1[aoff[m + 4]];
    if (st2) stgB(buf, 0, t + 2);
    SCHED0; BARRIER;
    asm volatile("s_waitcnt lgkmcnt(0)" ::: "memory");
    SCHED0;
    PHASE_MFMA(4)
    SCHED0;
    if (t < nt - 2)       { asm volatile("s_waitcnt vmcnt(8)" ::: "memory"); }
    else if (t == nt - 2) { asm volatile("s_waitcnt vmcnt(4)" ::: "memory"); }
    if (t < nt - 1) { BARRIER; SCHED0; }
#undef PHASE_MFMA
  }

#pragma unroll
  for (int n = 0; n < 4; ++n) {
    const long col = col0 + wn * 64 + n * 16 + fr;
    const float bv = bias[col];
#pragma unroll
    for (int m = 0; m < 8; ++m) {
#pragma unroll
      for (int j = 0; j < 4; ++j) {
        const long row = row0 + wm * 128 + m * 16 + g * 4 + j;
        const long off = row * N + col;
        float v = acc[m][n][j] + bv;
        if constexpr (EPI == 0) {
          ((u16*)outp)[off] = f2bf(v);
        } else if constexpr (EPI == 1) {
          float ge = 0.5f * v * (1.0f + erff(v * 0.70710678118654752f));
          ((u16*)outp)[off] = f2bf(ge);
        } else {
          ((float*)outp)[off] = v + res[off];
        }
      }
    }
  }
}

// ---------------------------------------------------------------------------
// Relative position index (matches _rel_index in reference)
// ---------------------------------------------------------------------------
template<int LQ>
__device__ __forceinline__ int rel_index(int q, int k) {
  if constexpr (LQ == 64) {
    const int qh = q >> 3, qw = q & 7, kh = k >> 4, kw = k & 15;
    return (qh - kh + 15) * 23 + (qw - kw + 15);
  } else {
    const int qh = q >> 4, qw = q & 15, kh = k >> 3, kw = k & 7;
    return (qh - kh + 7) * 23 + (qw - kw + 7);
  }
}

// ---------------------------------------------------------------------------
// Fused cross attention, one block per (head, batch). 256 threads, MFMA.
// ---------------------------------------------------------------------------
template<int LQ, int LK>
__global__ __launch_bounds__(256) void attn_kernel(
    const u16* __restrict__ Q, const u16* __restrict__ KV,
    const float* __restrict__ rpb, u16* __restrict__ O)
{
  constexpr int MT = LQ / 64;
  constexpr int NT = LK / 16;
  constexpr int KSPV = LK / 32;

  __shared__ __align__(16) u16 Qs[LQ * 64];
  __shared__ __align__(16) u16 Ks[LK * 64];
  __shared__ __align__(16) u16 Vt[64 * LK];
  __shared__ __align__(16) u16 Ps[LQ * LK];
  __shared__ float bias_s[529];

  const int h = blockIdx.x;
  const int b = blockIdx.y;
  const int tid = threadIdx.x;
  const int lane = tid & 63;
  const int w = tid >> 6;

  for (int i = tid; i < 529; i += 256) bias_s[i] = rpb[i * 12 + h];

#pragma unroll
  for (int it = 0; it < LQ * 8 / 256; ++it) {
    const int s = it * 256 + tid;
    const int r = s >> 3, sl2 = s & 7;
    bf16x8 v = *(const bf16x8*)&Q[(size_t)(b * LQ + r) * 768 + h * 64 + sl2 * 8];
    *(bf16x8*)&Qs[r * 64 + ((sl2 ^ (r & 7)) * 8)] = v;
  }
#pragma unroll
  for (int it = 0; it < LK * 8 / 256; ++it) {
    const int s = it * 256 + tid;
    const int r = s >> 3, sl2 = s & 7;
    bf16x8 v = *(const bf16x8*)&KV[(size_t)(b * LK + r) * 1536 + h * 64 + sl2 * 8];
    *(bf16x8*)&Ks[r * 64 + ((sl2 ^ (r & 7)) * 8)] = v;
  }
#pragma unroll
  for (int it = 0; it < LK * 8 / 256; ++it) {
    const int s = it * 256 + tid;
    const int r = s >> 3, sl2 = s & 7;
    const int d0 = sl2 * 8;
    bf16x8 v = *(const bf16x8*)&KV[(size_t)(b * LK + r) * 1536 + 768 + h * 64 + d0];
#pragma unroll
    for (int j = 0; j < 8; ++j) {
      const int d = d0 + j;
      Vt[d * LK + (((r >> 3) ^ (d & 7)) * 8) + (r & 7)] = (u16)v[j];
    }
  }
  __syncthreads();

  const int fr = lane & 15;
  const int g = lane >> 4;
  const int qbase = w * MT * 16;

  f32x4 sacc[MT][NT];
#pragma unroll
  for (int mt = 0; mt < MT; ++mt)
#pragma unroll
    for (int nt = 0; nt < NT; ++nt) sacc[mt][nt] = (f32x4){0.f, 0.f, 0.f, 0.f};

#pragma unroll
  for (int mt = 0; mt < MT; ++mt) {
    const int qr = qbase + mt * 16 + fr;
    bf16x8 aq0 = *(const bf16x8*)&Qs[qr * 64 + (((0 + g) ^ (qr & 7)) * 8)];
    bf16x8 aq1 = *(const bf16x8*)&Qs[qr * 64 + (((4 + g) ^ (qr & 7)) * 8)];
#pragma unroll
    for (int nt = 0; nt < NT; ++nt) {
      const int kr = nt * 16 + fr;
      bf16x8 bk0 = *(const bf16x8*)&Ks[kr * 64 + (((0 + g) ^ (kr & 7)) * 8)];
      bf16x8 bk1 = *(const bf16x8*)&Ks[kr * 64 + (((4 + g) ^ (kr & 7)) * 8)];
      sacc[mt][nt] = __builtin_amdgcn_mfma_f32_16x16x32_bf16(aq0, bk0, sacc[mt][nt], 0, 0, 0);
      sacc[mt][nt] = __builtin_amdgcn_mfma_f32_16x16x32_bf16(aq1, bk1, sacc[mt][nt], 0, 0, 0);
    }
  }

#pragma unroll
  for (int mt = 0; mt < MT; ++mt) {
#pragma unroll
    for (int reg = 0; reg < 4; ++reg) {
      const int q = qbase + mt * 16 + g * 4 + reg;
      float mx = -3.0e38f;
#pragma unroll
      for (int nt = 0; nt < NT; ++nt) {
        const int k = nt * 16 + fr;
        float s = sacc[mt][nt][reg] * 0.125f + bias_s[rel_index<LQ>(q, k)];
        sacc[mt][nt][reg] = s;
        mx = fmaxf(mx, s);
      }
      mx = fmaxf(mx, __shfl_xor(mx, 1));
      mx = fmaxf(mx, __shfl_xor(mx, 2));
      mx = fmaxf(mx, __shfl_xor(mx, 4));
      mx = fmaxf(mx, __shfl_xor(mx, 8));
      float sum = 0.f;
#pragma unroll
      for (int nt = 0; nt < NT; ++nt) {
        float p = __expf(sacc[mt][nt][reg] - mx);
        sacc[mt][nt][reg] = p;
        sum += p;
      }
      sum += __shfl_xor(sum, 1);
      sum += __shfl_xor(sum, 2);
      sum += __shfl_xor(sum, 4);
      sum += __shfl_xor(sum, 8);
      const float inv = 1.0f / sum;
#pragma unroll
      for (int nt = 0; nt < NT; ++nt) {
        const int k = nt * 16 + fr;
        Ps[q * LK + (((k >> 3) ^ (q & 7)) * 8) + (k & 7)] = f2bf(sacc[mt][nt][reg] * inv);
      }
    }
  }
  __syncthreads();

  f32x4 oacc[MT][4];
#pragma unroll
  for (int mt = 0; mt < MT; ++mt)
#pragma unroll
    for (int n = 0; n < 4; ++n) oacc[mt][n] = (f32x4){0.f, 0.f, 0.f, 0.f};

#pragma unroll
  for (int mt = 0; mt < MT; ++mt) {
    const int pr = qbase + mt * 16 + fr;
#pragma unroll
    for (int ks = 0; ks < KSPV; ++ks) {
      bf16x8 ap = *(const bf16x8*)&Ps[pr * LK + (((ks * 4 + g) ^ (pr & 7)) * 8)];
#pragma unroll
      for (int n = 0; n < 4; ++n) {
        const int d = n * 16 + fr;
        bf16x8 bv = *(const bf16x8*)&Vt[d * LK + (((ks * 4 + g) ^ (d & 7)) * 8)];
        oacc[mt][n] = __builtin_amdgcn_mfma_f32_16x16x32_bf16(ap, bv, oacc[mt][n], 0, 0, 0);
      }
    }
  }

#pragma unroll
  for (int mt = 0; mt < MT; ++mt)
#pragma unroll
    for (int n = 0; n < 4; ++n)
#pragma unroll
      for (int reg = 0; reg < 4; ++reg) {
        const int q = qbase + mt * 16 + g * 4 + reg;
        const int d = n * 16 + fr;
        O[(size_t)(b * LQ + q) * 768 + h * 64 + d] = f2bf(oacc[mt][n][reg]);
      }
}

// ---------------------------------------------------------------------------
// Host launcher
// ---------------------------------------------------------------------------
extern "C" void kernel_launch(void* const* d_in, const int* in_sizes, int n_in,
                              void* d_out, int out_size, void* d_ws, size_t ws_size,
                              hipStream_t stream)
{
  const float* z      = (const float*)d_in[0];
  const float* x      = (const float*)d_in[1];
  const float* zln1g  = (const float*)d_in[2];
  const float* zln1b  = (const float*)d_in[3];
  const float* xln1g  = (const float*)d_in[4];
  const float* xln1b  = (const float*)d_in[5];
  const float* zx_qw  = (const float*)d_in[6];
  const float* zx_qb  = (const float*)d_in[7];
  const float* zx_kvw = (const float*)d_in[8];
  const float* zx_kvb = (const float*)d_in[9];
  const float* zx_pw  = (const float*)d_in[10];
  const float* zx_pb  = (const float*)d_in[11];
  const float* zx_rpb = (const float*)d_in[12];
  const float* xz_qw  = (const float*)d_in[13];
  const float* xz_qb  = (const float*)d_in[14];
  const float* xz_kvw = (const float*)d_in[15];
  const float* xz_kvb = (const float*)d_in[16];
  const float* xz_pw  = (const float*)d_in[17];
  const float* xz_pb  = (const float*)d_in[18];
  const float* xz_rpb = (const float*)d_in[19];
  const float* zln2g  = (const float*)d_in[20];
  const float* zln2b  = (const float*)d_in[21];
  const float* zfc1w  = (const float*)d_in[22];
  const float* zfc1b  = (const float*)d_in[23];
  const float* zfc2w  = (const float*)d_in[24];
  const float* zfc2b  = (const float*)d_in[25];
  const float* xln2g  = (const float*)d_in[26];
  const float* xln2b  = (const float*)d_in[27];
  const float* xfc1w  = (const float*)d_in[28];
  const float* xfc1b  = (const float*)d_in[29];
  const float* xfc2w  = (const float*)d_in[30];
  const float* xfc2b  = (const float*)d_in[31];

  float* out = (float*)d_out;
  float* z2 = out;                       // 4096 x 768 f32
  float* x2 = out + 3145728;             // 16384 x 768 f32

  char* ws = (char*)d_ws;
  size_t off = 0;
  auto take = [&](size_t bytes) {
    char* p = ws + off;
    off += (bytes + 255) & ~(size_t)255;
    return p;
  };
  u16* w_zx_q  = (u16*)take(589824 * 2);
  u16* w_zx_kv = (u16*)take(1179648 * 2);
  u16* w_zx_p  = (u16*)take(589824 * 2);
  u16* w_xz_q  = (u16*)take(589824 * 2);
  u16* w_xz_kv = (u16*)take(1179648 * 2);
  u16* w_xz_p  = (u16*)take(589824 * 2);
  u16* w_zfc1  = (u16*)take(2359296 * 2);
  u16* w_zfc2  = (u16*)take(2359296 * 2);
  u16* w_xfc1  = (u16*)take(2359296 * 2);
  u16* w_xfc2  = (u16*)take(2359296 * 2);
  u16* regA    = (u16*)take(31457280);   // zn|xn -> ao_z|ao_x -> z2n|x2n

  const size_t need_full = off + 100663296;
  const bool full = (ws_size >= need_full);
  u16* regB = (u16*)take(full ? 100663296 : 94371840);

  u16* zn   = regA;
  u16* xn   = regA + 3145728;
  u16* q_z  = regB;
  u16* kv_x = regB + 3145728;
  u16* q_x  = regB + 3145728 + 25165824;
  u16* kv_z = regB + 3145728 + 25165824 + 12582912;
  u16* ao_z = zn;
  u16* ao_x = xn;
  u16* z2n  = zn;
  u16* x2n  = xn;
  u16* h    = regB;

  // 1. weights -> bf16
  Conv10 c;
  c.src[0] = zx_qw;  c.dst[0] = w_zx_q;  c.n[0] = 589824;
  c.src[1] = zx_kvw; c.dst[1] = w_zx_kv; c.n[1] = 1179648;
  c.src[2] = zx_pw;  c.dst[2] = w_zx_p;  c.n[2] = 589824;
  c.src[3] = xz_qw;  c.dst[3] = w_xz_q;  c.n[3] = 589824;
  c.src[4] = xz_kvw; c.dst[4] = w_xz_kv; c.n[4] = 1179648;
  c.src[5] = xz_pw;  c.dst[5] = w_xz_p;  c.n[5] = 589824;
  c.src[6] = zfc1w;  c.dst[6] = w_zfc1;  c.n[6] = 2359296;
  c.src[7] = zfc2w;  c.dst[7] = w_zfc2;  c.n[7] = 2359296;
  c.src[8] = xfc1w;  c.dst[8] = w_xfc1;  c.n[8] = 2359296;
  c.src[9] = xfc2w;  c.dst[9] = w_xfc2;  c.n[9] = 2359296;
  convert10<<<dim3(2304, 10), 256, 0, stream>>>(c);

  // 2. LN1
  ln_dual<<<5120, 256, 0, stream>>>(z, zln1g, zln1b, zn, 4096, x, xln1g, xln1b, xn);

  // 3. QKV projections
  gemm_bt<0><<<dim3(6, 32), 256, 0, stream>>>(zn, w_zx_q, zx_qb, nullptr, q_z, 4096, 768, 768);
  gemm8<0><<<dim3(6, 64), 512, 0, stream>>>(xn, w_zx_kv, zx_kvb, nullptr, kv_x, 16384, 1536, 768);
  gemm8<0><<<dim3(3, 64), 512, 0, stream>>>(xn, w_xz_q,  xz_qb,  nullptr, q_x,  16384, 768, 768);
  gemm_bt<0><<<dim3(12, 32), 256, 0, stream>>>(zn, w_xz_kv, xz_kvb, nullptr, kv_z, 4096, 1536, 768);

  // 4. attention
  attn_kernel<64, 256><<<dim3(12, 64), 256, 0, stream>>>(q_z, kv_x, zx_rpb, ao_z);
  attn_kernel<256, 64><<<dim3(12, 64), 256, 0, stream>>>(q_x, kv_z, xz_rpb, ao_x);

  // 5. output proj + residual
  gemm_bt<2><<<dim3(6, 32), 256, 0, stream>>>(ao_z, w_zx_p, zx_pb, z, z2, 4096, 768, 768);
  gemm8<2><<<dim3(3, 64), 512, 0, stream>>>(ao_x, w_xz_p, xz_pb, x, x2, 16384, 768, 768);

  // 6. LN2
  ln_dual<<<5120, 256, 0, stream>>>(z2, zln2g, zln2b, z2n, 4096, x2, xln2g, xln2b, x2n);

  // 7. MLPs
  gemm8<1><<<dim3(12, 16), 512, 0, stream>>>(z2n, w_zfc1, zfc1b, nullptr, h, 4096, 3072, 768);
  gemm_bt<2><<<dim3(6, 32), 256, 0, stream>>>(h, w_zfc2, zfc2b, z2, z2, 4096, 768, 3072);

  if (full) {
    gemm8<1><<<dim3(12, 64), 512, 0, stream>>>(x2n, w_xfc1, xfc1b, nullptr, h, 16384, 3072, 768);
    gemm8<2><<<dim3(3, 64),  512, 0, stream>>>(h, w_xfc2, xfc2b, x2, x2, 16384, 768, 3072);
  } else {
    gemm8<1><<<dim3(12, 32), 512, 0, stream>>>(x2n, w_xfc1, xfc1b, nullptr, h, 8192, 3072, 768);
    gemm8<2><<<dim3(3, 32),  512, 0, stream>>>(h, w_xfc2, xfc2b, x2, x2, 8192, 768, 3072);
    gemm8<1><<<dim3(12, 32), 512, 0, stream>>>(x2n + (size_t)8192 * 768, w_xfc1, xfc1b, nullptr, h, 8192, 3072, 768);
    gemm8<2><<<dim3(3, 32),  512, 0, stream>>>(h, w_xfc2, xfc2b, x2 + (size_t)8192 * 768, x2 + (size_t)8192 * 768, 8192, 768, 3072);
  }
}

// Round 6
// 746.954 us; speedup vs baseline: 1.1822x; 1.1822x over previous
//
#include <hip/hip_runtime.h>
#include <math.h>

typedef unsigned short u16;
typedef unsigned int u32;
typedef __attribute__((ext_vector_type(8))) short bf16x8;
typedef __attribute__((ext_vector_type(4))) float f32x4;
typedef __attribute__((ext_vector_type(4))) u16 u16x4;

__device__ __forceinline__ u16 f2bf(float f) {
  u32 u = __builtin_bit_cast(u32, f);
  u32 r = (u + 0x7fffu + ((u >> 16) & 1u)) >> 16;
  return (u16)r;
}

// fast exact-feeling gelu: v*sigmoid(1.5957691*v*(1+0.044715*v^2)); |err|<3e-3
__device__ __forceinline__ float gelu_f(float v) {
  float u = 1.5957691216057308f * v * (1.0f + 0.044715f * v * v);
  return v / (1.0f + __expf(-u));
}

__device__ __forceinline__ void async16(const void* g, void* l) {
  __builtin_amdgcn_global_load_lds(
      (__attribute__((address_space(1))) void*)(unsigned long long)(const char*)g,
      (__attribute__((address_space(3))) void*)l, 16, 0, 0);
}

// ---------------------------------------------------------------------------
// Weight f32 -> bf16 conversion (10 segments, one launch)
// ---------------------------------------------------------------------------
struct Conv10 {
  const float* src[10];
  u16* dst[10];
  int n[10];
};

__global__ __launch_bounds__(256) void convert10(Conv10 a) {
  const int seg = blockIdx.y;
  const long i = ((long)blockIdx.x * 256 + threadIdx.x) * 4;
  if (i >= a.n[seg]) return;
  float4 v = *(const float4*)&a.src[seg][i];
  u16x4 o;
  o.x = f2bf(v.x); o.y = f2bf(v.y); o.z = f2bf(v.z); o.w = f2bf(v.w);
  *(u16x4*)&a.dst[seg][i] = o;
}

// ---------------------------------------------------------------------------
// LayerNorm (two tensors fused in one launch), f32 in -> bf16 out, 1 wave/row
// ---------------------------------------------------------------------------
__global__ __launch_bounds__(256) void ln_dual(
    const float* __restrict__ in1, const float* __restrict__ g1, const float* __restrict__ b1,
    u16* __restrict__ out1, int rows1,
    const float* __restrict__ in2, const float* __restrict__ g2, const float* __restrict__ b2,
    u16* __restrict__ out2)
{
  const int w = threadIdx.x >> 6;
  const int lane = threadIdx.x & 63;
  const int row = blockIdx.x * 4 + w;
  const float* in; const float* gg; const float* bb; u16* out;
  if (row < rows1) { in = in1 + (size_t)row * 768; gg = g1; bb = b1; out = out1 + (size_t)row * 768; }
  else { const int r2 = row - rows1; in = in2 + (size_t)r2 * 768; gg = g2; bb = b2; out = out2 + (size_t)r2 * 768; }

  float4 v0 = *(const float4*)&in[lane * 4];
  float4 v1 = *(const float4*)&in[lane * 4 + 256];
  float4 v2 = *(const float4*)&in[lane * 4 + 512];
  float s = v0.x + v0.y + v0.z + v0.w + v1.x + v1.y + v1.z + v1.w + v2.x + v2.y + v2.z + v2.w;
  float s2 = v0.x*v0.x + v0.y*v0.y + v0.z*v0.z + v0.w*v0.w
           + v1.x*v1.x + v1.y*v1.y + v1.z*v1.z + v1.w*v1.w
           + v2.x*v2.x + v2.y*v2.y + v2.z*v2.z + v2.w*v2.w;
#pragma unroll
  for (int m = 1; m <= 32; m <<= 1) { s += __shfl_xor(s, m); s2 += __shfl_xor(s2, m); }
  const float mean = s * (1.0f / 768.0f);
  const float var = s2 * (1.0f / 768.0f) - mean * mean;
  const float rs = rsqrtf(var + 1e-5f);

#define LNSTORE(V, OFFS) { \
    float4 gv = *(const float4*)&gg[lane * 4 + OFFS]; \
    float4 bv = *(const float4*)&bb[lane * 4 + OFFS]; \
    u16x4 o; \
    o.x = f2bf((V.x - mean) * rs * gv.x + bv.x); \
    o.y = f2bf((V.y - mean) * rs * gv.y + bv.y); \
    o.z = f2bf((V.z - mean) * rs * gv.z + bv.z); \
    o.w = f2bf((V.w - mean) * rs * gv.w + bv.w); \
    *(u16x4*)&out[lane * 4 + OFFS] = o; }
  LNSTORE(v0, 0)
  LNSTORE(v1, 256)
  LNSTORE(v2, 512)
#undef LNSTORE
}

// ---------------------------------------------------------------------------
// gemm_bt: round-1 kernel (m97 structure), kept for small z-side GEMMs.
// ---------------------------------------------------------------------------
template<int EPI>
__global__ __launch_bounds__(256) void gemm_bt(
    const u16* __restrict__ A, const u16* __restrict__ W,
    const float* __restrict__ bias, const float* __restrict__ res,
    void* __restrict__ outp, int M, int N, int K)
{
  __shared__ __align__(16) u16 As[128 * 32];
  __shared__ __align__(16) u16 Bs[128 * 32];
  const int tid = threadIdx.x;
  const int lane = tid & 63;
  const int w = tid >> 6;
  const long row0 = (long)blockIdx.y * 128;
  const long col0 = (long)blockIdx.x * 128;

  const int lr0 = w * 32 + (lane >> 2);
  const int lr1 = lr0 + 16;
  const int sl = lane & 3;
  const int ss0 = sl ^ ((lr0 >> 1) & 3);
  const int ss1 = sl ^ ((lr1 >> 1) & 3);
  const u16* ga0 = A + (row0 + lr0) * (long)K + ss0 * 8;
  const u16* ga1 = A + (row0 + lr1) * (long)K + ss1 * 8;
  const u16* gb0 = W + (col0 + lr0) * (long)K + ss0 * 8;
  const u16* gb1 = W + (col0 + lr1) * (long)K + ss1 * 8;
  u16* la0 = &As[(w * 2 + 0) * 512];
  u16* la1 = &As[(w * 2 + 1) * 512];
  u16* lb0 = &Bs[(w * 2 + 0) * 512];
  u16* lb1 = &Bs[(w * 2 + 1) * 512];

  const int fr = lane & 15;
  const int g = lane >> 4;
  const int wr = (w >> 1) * 64;
  const int wc = (w & 1) * 64;

  f32x4 acc[4][4];
#pragma unroll
  for (int m = 0; m < 4; ++m)
#pragma unroll
    for (int n = 0; n < 4; ++n) acc[m][n] = (f32x4){0.f, 0.f, 0.f, 0.f};

  for (int k0 = 0; k0 < K; k0 += 32) {
    async16(ga0, la0); async16(ga1, la1);
    async16(gb0, lb0); async16(gb1, lb1);
    ga0 += 32; ga1 += 32; gb0 += 32; gb1 += 32;
    __syncthreads();
    bf16x8 af[4], bfr[4];
#pragma unroll
    for (int m = 0; m < 4; ++m) {
      const int r = wr + m * 16 + fr;
      af[m] = *(const bf16x8*)&As[r * 32 + ((g ^ ((r >> 1) & 3)) * 8)];
    }
#pragma unroll
    for (int n = 0; n < 4; ++n) {
      const int r = wc + n * 16 + fr;
      bfr[n] = *(const bf16x8*)&Bs[r * 32 + ((g ^ ((r >> 1) & 3)) * 8)];
    }
#pragma unroll
    for (int m = 0; m < 4; ++m)
#pragma unroll
      for (int n = 0; n < 4; ++n)
        acc[m][n] = __builtin_amdgcn_mfma_f32_16x16x32_bf16(af[m], bfr[n], acc[m][n], 0, 0, 0);
    __syncthreads();
  }

#pragma unroll
  for (int n = 0; n < 4; ++n) {
    const long col = col0 + wc + n * 16 + fr;
    const float bv = bias[col];
#pragma unroll
    for (int m = 0; m < 4; ++m) {
#pragma unroll
      for (int j = 0; j < 4; ++j) {
        const long row = row0 + wr + m * 16 + g * 4 + j;
        const long off = row * N + col;
        float v = acc[m][n][j] + bv;
        if constexpr (EPI == 0) {
          ((u16*)outp)[off] = f2bf(v);
        } else if constexpr (EPI == 1) {
          ((u16*)outp)[off] = f2bf(gelu_f(v));
        } else {
          ((float*)outp)[off] = v + res[off];
        }
      }
    }
  }
}

// ---------------------------------------------------------------------------
// gemm5: 256x128 tile, BK=32, 4 waves (2 wm x 2 wn), per-wave 128x64 output
// (acc 8x4 -> 0.375 KB LDS per MFMA). Double-buffered LDS = 48 KB, target
// ~190 VGPR -> 2 blocks/CU co-resident (TLP hides the per-step drain).
// Round-4-proven sync: stage(next) at top, compute(cur), one __syncthreads.
// Swizzle: slot ^ ((row>>1)&3), pre-applied on global source; linear dest.
// ---------------------------------------------------------------------------
template<int EPI>
__global__ __launch_bounds__(256, 2) void gemm5(
    const u16* __restrict__ A, const u16* __restrict__ W,
    const float* __restrict__ bias, const float* __restrict__ res,
    void* __restrict__ outp, int M, int N, int K)
{
  __shared__ __align__(16) u16 As[2][256 * 32];
  __shared__ __align__(16) u16 Bs[2][128 * 32];

  const int tid = threadIdx.x;
  const int lane = tid & 63;
  const int w = tid >> 6;
  const int wm = w >> 1;   // 0..1
  const int wn = w & 1;    // 0..1

  int flat = blockIdx.y * gridDim.x + blockIdx.x;
  const int nwg = gridDim.x * gridDim.y;
  if ((nwg & 7) == 0) flat = (flat & 7) * (nwg >> 3) + (flat >> 3);
  const int bx = flat % gridDim.x;
  const int by = flat / gridDim.x;
  const long row0 = (long)by * 256;
  const long col0 = (long)bx * 128;

  const u16* gA[4];
  const u16* gB[2];
#pragma unroll
  for (int l = 0; l < 4; ++l) {
    const int e = l * 256 + tid;
    const int r = e >> 2, sl = e & 3;
    gA[l] = A + (row0 + r) * (long)K + ((sl ^ ((r >> 1) & 3)) * 8);
  }
#pragma unroll
  for (int l = 0; l < 2; ++l) {
    const int e = l * 256 + tid;
    const int r = e >> 2, sl = e & 3;
    gB[l] = W + (col0 + r) * (long)K + ((sl ^ ((r >> 1) & 3)) * 8);
  }

  const int fr = lane & 15;
  const int g = lane >> 4;

  f32x4 acc[8][4];
#pragma unroll
  for (int m = 0; m < 8; ++m)
#pragma unroll
    for (int n = 0; n < 4; ++n) acc[m][n] = (f32x4){0.f, 0.f, 0.f, 0.f};

  auto stage = [&](int buf, long ko) {
#pragma unroll
    for (int l = 0; l < 4; ++l) async16(gA[l] + ko, &As[buf][(l * 256 + tid) * 8]);
#pragma unroll
    for (int l = 0; l < 2; ++l) async16(gB[l] + ko, &Bs[buf][(l * 256 + tid) * 8]);
  };

  const int nt = K / 32;
  stage(0, 0);
  __syncthreads();

  int cur = 0;
  for (int t = 0; t < nt; ++t) {
    if (t + 1 < nt) stage(cur ^ 1, (long)(t + 1) * 32);
    const u16* Ab = As[cur];
    const u16* Bb = Bs[cur];
    bf16x8 bfr[4];
#pragma unroll
    for (int n = 0; n < 4; ++n) {
      const int r = wn * 64 + n * 16 + fr;
      bfr[n] = *(const bf16x8*)&Bb[r * 32 + ((g ^ ((r >> 1) & 3)) * 8)];
    }
#pragma unroll
    for (int m = 0; m < 8; ++m) {
      const int r = wm * 128 + m * 16 + fr;
      bf16x8 af = *(const bf16x8*)&Ab[r * 32 + ((g ^ ((r >> 1) & 3)) * 8)];
#pragma unroll
      for (int n = 0; n < 4; ++n)
        acc[m][n] = __builtin_amdgcn_mfma_f32_16x16x32_bf16(af, bfr[n], acc[m][n], 0, 0, 0);
    }
    __syncthreads();
    cur ^= 1;
  }

#pragma unroll
  for (int n = 0; n < 4; ++n) {
    const long col = col0 + wn * 64 + n * 16 + fr;
    const float bv = bias[col];
#pragma unroll
    for (int m = 0; m < 8; ++m) {
#pragma unroll
      for (int j = 0; j < 4; ++j) {
        const long row = row0 + wm * 128 + m * 16 + g * 4 + j;
        const long off = row * N + col;
        float v = acc[m][n][j] + bv;
        if constexpr (EPI == 0) {
          ((u16*)outp)[off] = f2bf(v);
        } else if constexpr (EPI == 1) {
          ((u16*)outp)[off] = f2bf(gelu_f(v));
        } else {
          ((float*)outp)[off] = v + res[off];
        }
      }
    }
  }
}

// ---------------------------------------------------------------------------
// Relative position index (matches _rel_index in reference)
// ---------------------------------------------------------------------------
template<int LQ>
__device__ __forceinline__ int rel_index(int q, int k) {
  if constexpr (LQ == 64) {
    const int qh = q >> 3, qw = q & 7, kh = k >> 4, kw = k & 15;
    return (qh - kh + 15) * 23 + (qw - kw + 15);
  } else {
    const int qh = q >> 4, qw = q & 15, kh = k >> 3, kw = k & 7;
    return (qh - kh + 7) * 23 + (qw - kw + 7);
  }
}

// ---------------------------------------------------------------------------
// Fused cross attention, one block per (head, batch). 256 threads, MFMA.
// ---------------------------------------------------------------------------
template<int LQ, int LK>
__global__ __launch_bounds__(256) void attn_kernel(
    const u16* __restrict__ Q, const u16* __restrict__ KV,
    const float* __restrict__ rpb, u16* __restrict__ O)
{
  constexpr int MT = LQ / 64;
  constexpr int NT = LK / 16;
  constexpr int KSPV = LK / 32;

  __shared__ __align__(16) u16 Qs[LQ * 64];
  __shared__ __align__(16) u16 Ks[LK * 64];
  __shared__ __align__(16) u16 Vt[64 * LK];
  __shared__ __align__(16) u16 Ps[LQ * LK];
  __shared__ float bias_s[529];

  const int h = blockIdx.x;
  const int b = blockIdx.y;
  const int tid = threadIdx.x;
  const int lane = tid & 63;
  const int w = tid >> 6;

  for (int i = tid; i < 529; i += 256) bias_s[i] = rpb[i * 12 + h];

#pragma unroll
  for (int it = 0; it < LQ * 8 / 256; ++it) {
    const int s = it * 256 + tid;
    const int r = s >> 3, sl2 = s & 7;
    bf16x8 v = *(const bf16x8*)&Q[(size_t)(b * LQ + r) * 768 + h * 64 + sl2 * 8];
    *(bf16x8*)&Qs[r * 64 + ((sl2 ^ (r & 7)) * 8)] = v;
  }
#pragma unroll
  for (int it = 0; it < LK * 8 / 256; ++it) {
    const int s = it * 256 + tid;
    const int r = s >> 3, sl2 = s & 7;
    bf16x8 v = *(const bf16x8*)&KV[(size_t)(b * LK + r) * 1536 + h * 64 + sl2 * 8];
    *(bf16x8*)&Ks[r * 64 + ((sl2 ^ (r & 7)) * 8)] = v;
  }
#pragma unroll
  for (int it = 0; it < LK * 8 / 256; ++it) {
    const int s = it * 256 + tid;
    const int r = s >> 3, sl2 = s & 7;
    const int d0 = sl2 * 8;
    bf16x8 v = *(const bf16x8*)&KV[(size_t)(b * LK + r) * 1536 + 768 + h * 64 + d0];
#pragma unroll
    for (int j = 0; j < 8; ++j) {
      const int d = d0 + j;
      Vt[d * LK + (((r >> 3) ^ (d & 7)) * 8) + (r & 7)] = (u16)v[j];
    }
  }
  __syncthreads();

  const int fr = lane & 15;
  const int g = lane >> 4;
  const int qbase = w * MT * 16;

  f32x4 sacc[MT][NT];
#pragma unroll
  for (int mt = 0; mt < MT; ++mt)
#pragma unroll
    for (int nt = 0; nt < NT; ++nt) sacc[mt][nt] = (f32x4){0.f, 0.f, 0.f, 0.f};

#pragma unroll
  for (int mt = 0; mt < MT; ++mt) {
    const int qr = qbase + mt * 16 + fr;
    bf16x8 aq0 = *(const bf16x8*)&Qs[qr * 64 + (((0 + g) ^ (qr & 7)) * 8)];
    bf16x8 aq1 = *(const bf16x8*)&Qs[qr * 64 + (((4 + g) ^ (qr & 7)) * 8)];
#pragma unroll
    for (int nt = 0; nt < NT; ++nt) {
      const int kr = nt * 16 + fr;
      bf16x8 bk0 = *(const bf16x8*)&Ks[kr * 64 + (((0 + g) ^ (kr & 7)) * 8)];
      bf16x8 bk1 = *(const bf16x8*)&Ks[kr * 64 + (((4 + g) ^ (kr & 7)) * 8)];
      sacc[mt][nt] = __builtin_amdgcn_mfma_f32_16x16x32_bf16(aq0, bk0, sacc[mt][nt], 0, 0, 0);
      sacc[mt][nt] = __builtin_amdgcn_mfma_f32_16x16x32_bf16(aq1, bk1, sacc[mt][nt], 0, 0, 0);
    }
  }

#pragma unroll
  for (int mt = 0; mt < MT; ++mt) {
#pragma unroll
    for (int reg = 0; reg < 4; ++reg) {
      const int q = qbase + mt * 16 + g * 4 + reg;
      float mx = -3.0e38f;
#pragma unroll
      for (int nt = 0; nt < NT; ++nt) {
        const int k = nt * 16 + fr;
        float s = sacc[mt][nt][reg] * 0.125f + bias_s[rel_index<LQ>(q, k)];
        sacc[mt][nt][reg] = s;
        mx = fmaxf(mx, s);
      }
      mx = fmaxf(mx, __shfl_xor(mx, 1));
      mx = fmaxf(mx, __shfl_xor(mx, 2));
      mx = fmaxf(mx, __shfl_xor(mx, 4));
      mx = fmaxf(mx, __shfl_xor(mx, 8));
      float sum = 0.f;
#pragma unroll
      for (int nt = 0; nt < NT; ++nt) {
        float p = __expf(sacc[mt][nt][reg] - mx);
        sacc[mt][nt][reg] = p;
        sum += p;
      }
      sum += __shfl_xor(sum, 1);
      sum += __shfl_xor(sum, 2);
      sum += __shfl_xor(sum, 4);
      sum += __shfl_xor(sum, 8);
      const float inv = 1.0f / sum;
#pragma unroll
      for (int nt = 0; nt < NT; ++nt) {
        const int k = nt * 16 + fr;
        Ps[q * LK + (((k >> 3) ^ (q & 7)) * 8) + (k & 7)] = f2bf(sacc[mt][nt][reg] * inv);
      }
    }
  }
  __syncthreads();

  f32x4 oacc[MT][4];
#pragma unroll
  for (int mt = 0; mt < MT; ++mt)
#pragma unroll
    for (int n = 0; n < 4; ++n) oacc[mt][n] = (f32x4){0.f, 0.f, 0.f, 0.f};

#pragma unroll
  for (int mt = 0; mt < MT; ++mt) {
    const int pr = qbase + mt * 16 + fr;
#pragma unroll
    for (int ks = 0; ks < KSPV; ++ks) {
      bf16x8 ap = *(const bf16x8*)&Ps[pr * LK + (((ks * 4 + g) ^ (pr & 7)) * 8)];
#pragma unroll
      for (int n = 0; n < 4; ++n) {
        const int d = n * 16 + fr;
        bf16x8 bv = *(const bf16x8*)&Vt[d * LK + (((ks * 4 + g) ^ (d & 7)) * 8)];
        oacc[mt][n] = __builtin_amdgcn_mfma_f32_16x16x32_bf16(ap, bv, oacc[mt][n], 0, 0, 0);
      }
    }
  }

#pragma unroll
  for (int mt = 0; mt < MT; ++mt)
#pragma unroll
    for (int n = 0; n < 4; ++n)
#pragma unroll
      for (int reg = 0; reg < 4; ++reg) {
        const int q = qbase + mt * 16 + g * 4 + reg;
        const int d = n * 16 + fr;
        O[(size_t)(b * LQ + q) * 768 + h * 64 + d] = f2bf(oacc[mt][n][reg]);
      }
}

// ---------------------------------------------------------------------------
// Host launcher
// ---------------------------------------------------------------------------
extern "C" void kernel_launch(void* const* d_in, const int* in_sizes, int n_in,
                              void* d_out, int out_size, void* d_ws, size_t ws_size,
                              hipStream_t stream)
{
  const float* z      = (const float*)d_in[0];
  const float* x      = (const float*)d_in[1];
  const float* zln1g  = (const float*)d_in[2];
  const float* zln1b  = (const float*)d_in[3];
  const float* xln1g  = (const float*)d_in[4];
  const float* xln1b  = (const float*)d_in[5];
  const float* zx_qw  = (const float*)d_in[6];
  const float* zx_qb  = (const float*)d_in[7];
  const float* zx_kvw = (const float*)d_in[8];
  const float* zx_kvb = (const float*)d_in[9];
  const float* zx_pw  = (const float*)d_in[10];
  const float* zx_pb  = (const float*)d_in[11];
  const float* zx_rpb = (const float*)d_in[12];
  const float* xz_qw  = (const float*)d_in[13];
  const float* xz_qb  = (const float*)d_in[14];
  const float* xz_kvw = (const float*)d_in[15];
  const float* xz_kvb = (const float*)d_in[16];
  const float* xz_pw  = (const float*)d_in[17];
  const float* xz_pb  = (const float*)d_in[18];
  const float* xz_rpb = (const float*)d_in[19];
  const float* zln2g  = (const float*)d_in[20];
  const float* zln2b  = (const float*)d_in[21];
  const float* zfc1w  = (const float*)d_in[22];
  const float* zfc1b  = (const float*)d_in[23];
  const float* zfc2w  = (const float*)d_in[24];
  const float* zfc2b  = (const float*)d_in[25];
  const float* xln2g  = (const float*)d_in[26];
  const float* xln2b  = (const float*)d_in[27];
  const float* xfc1w  = (const float*)d_in[28];
  const float* xfc1b  = (const float*)d_in[29];
  const float* xfc2w  = (const float*)d_in[30];
  const float* xfc2b  = (const float*)d_in[31];

  float* out = (float*)d_out;
  float* z2 = out;                       // 4096 x 768 f32
  float* x2 = out + 3145728;             // 16384 x 768 f32

  char* ws = (char*)d_ws;
  size_t off = 0;
  auto take = [&](size_t bytes) {
    char* p = ws + off;
    off += (bytes + 255) & ~(size_t)255;
    return p;
  };
  u16* w_zx_q  = (u16*)take(589824 * 2);
  u16* w_zx_kv = (u16*)take(1179648 * 2);
  u16* w_zx_p  = (u16*)take(589824 * 2);
  u16* w_xz_q  = (u16*)take(589824 * 2);
  u16* w_xz_kv = (u16*)take(1179648 * 2);
  u16* w_xz_p  = (u16*)take(589824 * 2);
  u16* w_zfc1  = (u16*)take(2359296 * 2);
  u16* w_zfc2  = (u16*)take(2359296 * 2);
  u16* w_xfc1  = (u16*)take(2359296 * 2);
  u16* w_xfc2  = (u16*)take(2359296 * 2);
  u16* regA    = (u16*)take(31457280);   // zn|xn -> ao_z|ao_x -> z2n|x2n

  const size_t need_full = off + 100663296;
  const bool full = (ws_size >= need_full);
  u16* regB = (u16*)take(full ? 100663296 : 94371840);

  u16* zn   = regA;
  u16* xn   = regA + 3145728;
  u16* q_z  = regB;
  u16* kv_x = regB + 3145728;
  u16* q_x  = regB + 3145728 + 25165824;
  u16* kv_z = regB + 3145728 + 25165824 + 12582912;
  u16* ao_z = zn;
  u16* ao_x = xn;
  u16* z2n  = zn;
  u16* x2n  = xn;
  u16* h    = regB;

  // 1. weights -> bf16
  Conv10 c;
  c.src[0] = zx_qw;  c.dst[0] = w_zx_q;  c.n[0] = 589824;
  c.src[1] = zx_kvw; c.dst[1] = w_zx_kv; c.n[1] = 1179648;
  c.src[2] = zx_pw;  c.dst[2] = w_zx_p;  c.n[2] = 589824;
  c.src[3] = xz_qw;  c.dst[3] = w_xz_q;  c.n[3] = 589824;
  c.src[4] = xz_kvw; c.dst[4] = w_xz_kv; c.n[4] = 1179648;
  c.src[5] = xz_pw;  c.dst[5] = w_xz_p;  c.n[5] = 589824;
  c.src[6] = zfc1w;  c.dst[6] = w_zfc1;  c.n[6] = 2359296;
  c.src[7] = zfc2w;  c.dst[7] = w_zfc2;  c.n[7] = 2359296;
  c.src[8] = xfc1w;  c.dst[8] = w_xfc1;  c.n[8] = 2359296;
  c.src[9] = xfc2w;  c.dst[9] = w_xfc2;  c.n[9] = 2359296;
  convert10<<<dim3(2304, 10), 256, 0, stream>>>(c);

  // 2. LN1
  ln_dual<<<5120, 256, 0, stream>>>(z, zln1g, zln1b, zn, 4096, x, xln1g, xln1b, xn);

  // 3. QKV projections
  gemm_bt<0><<<dim3(6, 32), 256, 0, stream>>>(zn, w_zx_q, zx_qb, nullptr, q_z, 4096, 768, 768);
  gemm5<0><<<dim3(12, 64), 256, 0, stream>>>(xn, w_zx_kv, zx_kvb, nullptr, kv_x, 16384, 1536, 768);
  gemm5<0><<<dim3(6, 64),  256, 0, stream>>>(xn, w_xz_q,  xz_qb,  nullptr, q_x,  16384, 768, 768);
  gemm_bt<0><<<dim3(12, 32), 256, 0, stream>>>(zn, w_xz_kv, xz_kvb, nullptr, kv_z, 4096, 1536, 768);

  // 4. attention
  attn_kernel<64, 256><<<dim3(12, 64), 256, 0, stream>>>(q_z, kv_x, zx_rpb, ao_z);
  attn_kernel<256, 64><<<dim3(12, 64), 256, 0, stream>>>(q_x, kv_z, xz_rpb, ao_x);

  // 5. output proj + residual
  gemm_bt<2><<<dim3(6, 32), 256, 0, stream>>>(ao_z, w_zx_p, zx_pb, z, z2, 4096, 768, 768);
  gemm5<2><<<dim3(6, 64), 256, 0, stream>>>(ao_x, w_xz_p, xz_pb, x, x2, 16384, 768, 768);

  // 6. LN2
  ln_dual<<<5120, 256, 0, stream>>>(z2, zln2g, zln2b, z2n, 4096, x2, xln2g, xln2b, x2n);

  // 7. MLPs
  gemm5<1><<<dim3(24, 16), 256, 0, stream>>>(z2n, w_zfc1, zfc1b, nullptr, h, 4096, 3072, 768);
  gemm_bt<2><<<dim3(6, 32), 256, 0, stream>>>(h, w_zfc2, zfc2b, z2, z2, 4096, 768, 3072);

  if (full) {
    gemm5<1><<<dim3(24, 64), 256, 0, stream>>>(x2n, w_xfc1, xfc1b, nullptr, h, 16384, 3072, 768);
    gemm5<2><<<dim3(6, 64),  256, 0, stream>>>(h, w_xfc2, xfc2b, x2, x2, 16384, 768, 3072);
  } else {
    gemm5<1><<<dim3(24, 32), 256, 0, stream>>>(x2n, w_xfc1, xfc1b, nullptr, h, 8192, 3072, 768);
    gemm5<2><<<dim3(6, 32),  256, 0, stream>>>(h, w_xfc2, xfc2b, x2, x2, 8192, 768, 3072);
    gemm5<1><<<dim3(24, 32), 256, 0, stream>>>(x2n + (size_t)8192 * 768, w_xfc1, xfc1b, nullptr, h, 8192, 3072, 768);
    gemm5<2><<<dim3(6, 32),  256, 0, stream>>>(h, w_xfc2, xfc2b, x2 + (size_t)8192 * 768, x2 + (size_t)8192 * 768, 8192, 768, 3072);
  }
}

// Round 7
// 700.500 us; speedup vs baseline: 1.2606x; 1.0663x over previous
//
#include <hip/hip_runtime.h>
#include <math.h>

typedef unsigned short u16;
typedef unsigned int u32;
typedef __attribute__((ext_vector_type(8))) short bf16x8;
typedef __attribute__((ext_vector_type(4))) float f32x4;
typedef __attribute__((ext_vector_type(4))) u16 u16x4;

__device__ __forceinline__ u16 f2bf(float f) {
  u32 u = __builtin_bit_cast(u32, f);
  u32 r = (u + 0x7fffu + ((u >> 16) & 1u)) >> 16;
  return (u16)r;
}

// fast gelu: v*sigmoid(1.5957691*v*(1+0.044715*v^2)); |err|<3e-3 << 0.1175 thr
__device__ __forceinline__ float gelu_f(float v) {
  float u = 1.5957691216057308f * v * (1.0f + 0.044715f * v * v);
  return v / (1.0f + __expf(-u));
}

__device__ __forceinline__ void async16(const void* g, void* l) {
  __builtin_amdgcn_global_load_lds(
      (__attribute__((address_space(1))) void*)(unsigned long long)(const char*)g,
      (__attribute__((address_space(3))) void*)l, 16, 0, 0);
}

#define SCHED0 __builtin_amdgcn_sched_barrier(0)
#define BARRIER __builtin_amdgcn_s_barrier()

// ---------------------------------------------------------------------------
// Weight f32 -> bf16 conversion (10 segments, one launch)
// ---------------------------------------------------------------------------
struct Conv10 {
  const float* src[10];
  u16* dst[10];
  int n[10];
};

__global__ __launch_bounds__(256) void convert10(Conv10 a) {
  const int seg = blockIdx.y;
  const long i = ((long)blockIdx.x * 256 + threadIdx.x) * 4;
  if (i >= a.n[seg]) return;
  float4 v = *(const float4*)&a.src[seg][i];
  u16x4 o;
  o.x = f2bf(v.x); o.y = f2bf(v.y); o.z = f2bf(v.z); o.w = f2bf(v.w);
  *(u16x4*)&a.dst[seg][i] = o;
}

// pack two 2304-col bias vectors from 4 inputs
__global__ __launch_bounds__(256) void pack_bias(
    const float* __restrict__ zq, const float* __restrict__ zkv,
    const float* __restrict__ xq, const float* __restrict__ xkv,
    float* __restrict__ bz, float* __restrict__ bx)
{
  const int i = blockIdx.x * 256 + threadIdx.x;
  if (i >= 2304) return;
  bz[i] = (i < 768) ? zq[i] : zkv[i - 768];
  bx[i] = (i < 768) ? xq[i] : xkv[i - 768];
}

// ---------------------------------------------------------------------------
// LayerNorm (two tensors fused in one launch), f32 in -> bf16 out, 1 wave/row
// ---------------------------------------------------------------------------
__global__ __launch_bounds__(256) void ln_dual(
    const float* __restrict__ in1, const float* __restrict__ g1, const float* __restrict__ b1,
    u16* __restrict__ out1, int rows1,
    const float* __restrict__ in2, const float* __restrict__ g2, const float* __restrict__ b2,
    u16* __restrict__ out2)
{
  const int w = threadIdx.x >> 6;
  const int lane = threadIdx.x & 63;
  const int row = blockIdx.x * 4 + w;
  const float* in; const float* gg; const float* bb; u16* out;
  if (row < rows1) { in = in1 + (size_t)row * 768; gg = g1; bb = b1; out = out1 + (size_t)row * 768; }
  else { const int r2 = row - rows1; in = in2 + (size_t)r2 * 768; gg = g2; bb = b2; out = out2 + (size_t)r2 * 768; }

  float4 v0 = *(const float4*)&in[lane * 4];
  float4 v1 = *(const float4*)&in[lane * 4 + 256];
  float4 v2 = *(const float4*)&in[lane * 4 + 512];
  float s = v0.x + v0.y + v0.z + v0.w + v1.x + v1.y + v1.z + v1.w + v2.x + v2.y + v2.z + v2.w;
  float s2 = v0.x*v0.x + v0.y*v0.y + v0.z*v0.z + v0.w*v0.w
           + v1.x*v1.x + v1.y*v1.y + v1.z*v1.z + v1.w*v1.w
           + v2.x*v2.x + v2.y*v2.y + v2.z*v2.z + v2.w*v2.w;
#pragma unroll
  for (int m = 1; m <= 32; m <<= 1) { s += __shfl_xor(s, m); s2 += __shfl_xor(s2, m); }
  const float mean = s * (1.0f / 768.0f);
  const float var = s2 * (1.0f / 768.0f) - mean * mean;
  const float rs = rsqrtf(var + 1e-5f);

#define LNSTORE(V, OFFS) { \
    float4 gv = *(const float4*)&gg[lane * 4 + OFFS]; \
    float4 bv = *(const float4*)&bb[lane * 4 + OFFS]; \
    u16x4 o; \
    o.x = f2bf((V.x - mean) * rs * gv.x + bv.x); \
    o.y = f2bf((V.y - mean) * rs * gv.y + bv.y); \
    o.z = f2bf((V.z - mean) * rs * gv.z + bv.z); \
    o.w = f2bf((V.w - mean) * rs * gv.w + bv.w); \
    *(u16x4*)&out[lane * 4 + OFFS] = o; }
  LNSTORE(v0, 0)
  LNSTORE(v1, 256)
  LNSTORE(v2, 512)
#undef LNSTORE
}

// ---------------------------------------------------------------------------
// gemm_bt: m97-structure 128x128 kernel for z-side GEMMs (n-inner epilogue).
// ---------------------------------------------------------------------------
template<int EPI>
__global__ __launch_bounds__(256) void gemm_bt(
    const u16* __restrict__ A, const u16* __restrict__ W,
    const float* __restrict__ bias, const float* __restrict__ res,
    void* __restrict__ outp, int M, int N, int K)
{
  __shared__ __align__(16) u16 As[128 * 32];
  __shared__ __align__(16) u16 Bs[128 * 32];
  const int tid = threadIdx.x;
  const int lane = tid & 63;
  const int w = tid >> 6;
  const long row0 = (long)blockIdx.y * 128;
  const long col0 = (long)blockIdx.x * 128;

  const int lr0 = w * 32 + (lane >> 2);
  const int lr1 = lr0 + 16;
  const int sl = lane & 3;
  const int ss0 = sl ^ ((lr0 >> 1) & 3);
  const int ss1 = sl ^ ((lr1 >> 1) & 3);
  const u16* ga0 = A + (row0 + lr0) * (long)K + ss0 * 8;
  const u16* ga1 = A + (row0 + lr1) * (long)K + ss1 * 8;
  const u16* gb0 = W + (col0 + lr0) * (long)K + ss0 * 8;
  const u16* gb1 = W + (col0 + lr1) * (long)K + ss1 * 8;
  u16* la0 = &As[(w * 2 + 0) * 512];
  u16* la1 = &As[(w * 2 + 1) * 512];
  u16* lb0 = &Bs[(w * 2 + 0) * 512];
  u16* lb1 = &Bs[(w * 2 + 1) * 512];

  const int fr = lane & 15;
  const int g = lane >> 4;
  const int wr = (w >> 1) * 64;
  const int wc = (w & 1) * 64;

  f32x4 acc[4][4];
#pragma unroll
  for (int m = 0; m < 4; ++m)
#pragma unroll
    for (int n = 0; n < 4; ++n) acc[m][n] = (f32x4){0.f, 0.f, 0.f, 0.f};

  for (int k0 = 0; k0 < K; k0 += 32) {
    async16(ga0, la0); async16(ga1, la1);
    async16(gb0, lb0); async16(gb1, lb1);
    ga0 += 32; ga1 += 32; gb0 += 32; gb1 += 32;
    __syncthreads();
    bf16x8 af[4], bfr[4];
#pragma unroll
    for (int m = 0; m < 4; ++m) {
      const int r = wr + m * 16 + fr;
      af[m] = *(const bf16x8*)&As[r * 32 + ((g ^ ((r >> 1) & 3)) * 8)];
    }
#pragma unroll
    for (int n = 0; n < 4; ++n) {
      const int r = wc + n * 16 + fr;
      bfr[n] = *(const bf16x8*)&Bs[r * 32 + ((g ^ ((r >> 1) & 3)) * 8)];
    }
#pragma unroll
    for (int m = 0; m < 4; ++m)
#pragma unroll
      for (int n = 0; n < 4; ++n)
        acc[m][n] = __builtin_amdgcn_mfma_f32_16x16x32_bf16(af[m], bfr[n], acc[m][n], 0, 0, 0);
    __syncthreads();
  }

  float bv[4];
#pragma unroll
  for (int n = 0; n < 4; ++n) bv[n] = bias[col0 + wc + n * 16 + fr];
#pragma unroll
  for (int m = 0; m < 4; ++m) {
#pragma unroll
    for (int j = 0; j < 4; ++j) {
      const long row = row0 + wr + m * 16 + g * 4 + j;
      const long base = row * N + col0 + wc + fr;
#pragma unroll
      for (int n = 0; n < 4; ++n) {
        float v = acc[m][n][j] + bv[n];
        if constexpr (EPI == 0) {
          ((u16*)outp)[base + n * 16] = f2bf(v);
        } else if constexpr (EPI == 1) {
          ((u16*)outp)[base + n * 16] = f2bf(gelu_f(v));
        } else {
          ((float*)outp)[base + n * 16] = v + res[base + n * 16];
        }
      }
    }
  }
}

// ---------------------------------------------------------------------------
// gemm5: 256x128 tile, BK=32, 4 waves, per-wave 128x64 output.
// 3 LDS buffers (74 KB -> 2 blocks/CU), prefetch depth 2, counted waits:
// per step ONE {vmcnt(6) lgkmcnt(0); s_barrier} — the wait covers only the
// t+1 loads (age ~2 steps ~ HBM latency); t+2's 6 loads stay in flight
// across the barrier. Tail: vmcnt(0) before the last iteration.
// WAR: buffer re-staged at step t was read at t-1; those reads retired at
// the lgkmcnt(0)-before-barrier ending t-1.
// Swizzle: slot ^ ((row>>1)&3), pre-applied on global source; linear dest.
// ---------------------------------------------------------------------------
template<int EPI>
__global__ __launch_bounds__(256, 2) void gemm5(
    const u16* __restrict__ A, const u16* __restrict__ W,
    const float* __restrict__ bias, const float* __restrict__ res,
    void* __restrict__ outp, int M, int N, int K)
{
  __shared__ __align__(16) u16 As[3][256 * 32];
  __shared__ __align__(16) u16 Bs[3][128 * 32];

  const int tid = threadIdx.x;
  const int lane = tid & 63;
  const int w = tid >> 6;
  const int wm = w >> 1;   // 0..1
  const int wn = w & 1;    // 0..1

  int flat = blockIdx.y * gridDim.x + blockIdx.x;
  const int nwg = gridDim.x * gridDim.y;
  if ((nwg & 7) == 0) flat = (flat & 7) * (nwg >> 3) + (flat >> 3);
  const int bx = flat % gridDim.x;
  const int by = flat / gridDim.x;
  const long row0 = (long)by * 256;
  const long col0 = (long)bx * 128;

  const u16* gA[4];
  const u16* gB[2];
#pragma unroll
  for (int l = 0; l < 4; ++l) {
    const int e = l * 256 + tid;
    const int r = e >> 2, sl = e & 3;
    gA[l] = A + (row0 + r) * (long)K + ((sl ^ ((r >> 1) & 3)) * 8);
  }
#pragma unroll
  for (int l = 0; l < 2; ++l) {
    const int e = l * 256 + tid;
    const int r = e >> 2, sl = e & 3;
    gB[l] = W + (col0 + r) * (long)K + ((sl ^ ((r >> 1) & 3)) * 8);
  }

  const int fr = lane & 15;
  const int g = lane >> 4;

  f32x4 acc[8][4];
#pragma unroll
  for (int m = 0; m < 8; ++m)
#pragma unroll
    for (int n = 0; n < 4; ++n) acc[m][n] = (f32x4){0.f, 0.f, 0.f, 0.f};

  auto stage = [&](u16* ab, u16* bb, long ko) {
#pragma unroll
    for (int l = 0; l < 4; ++l) async16(gA[l] + ko, &ab[(l * 256 + tid) * 8]);
#pragma unroll
    for (int l = 0; l < 2; ++l) async16(gB[l] + ko, &bb[(l * 256 + tid) * 8]);
  };

  const int nt = K / 32;
  u16 *a0 = &As[0][0], *a1 = &As[1][0], *a2 = &As[2][0];
  u16 *b0 = &Bs[0][0], *b1 = &Bs[1][0], *b2 = &Bs[2][0];

  // prologue: 2 tiles in flight, wait tile 0 only (vmcnt leaves t1's 6)
  stage(a0, b0, 0);
  stage(a1, b1, 32);
  SCHED0;
  asm volatile("s_waitcnt vmcnt(6)" ::: "memory");
  BARRIER;
  SCHED0;

  for (int t = 0; t < nt; ++t) {
    if (t + 2 < nt) stage(a2, b2, (long)(t + 2) * 32);
    SCHED0;
    bf16x8 bfr[4];
#pragma unroll
    for (int n = 0; n < 4; ++n) {
      const int r = wn * 64 + n * 16 + fr;
      bfr[n] = *(const bf16x8*)&b0[r * 32 + ((g ^ ((r >> 1) & 3)) * 8)];
    }
#pragma unroll
    for (int m = 0; m < 8; ++m) {
      const int r = wm * 128 + m * 16 + fr;
      bf16x8 af = *(const bf16x8*)&a0[r * 32 + ((g ^ ((r >> 1) & 3)) * 8)];
#pragma unroll
      for (int n = 0; n < 4; ++n)
        acc[m][n] = __builtin_amdgcn_mfma_f32_16x16x32_bf16(af, bfr[n], acc[m][n], 0, 0, 0);
    }
    SCHED0;
    if (t + 2 < nt) {
      asm volatile("s_waitcnt vmcnt(6) lgkmcnt(0)" ::: "memory");
    } else if (t + 1 < nt) {
      asm volatile("s_waitcnt vmcnt(0) lgkmcnt(0)" ::: "memory");
    }
    if (t + 1 < nt) { BARRIER; SCHED0; }
    u16* ta = a0; a0 = a1; a1 = a2; a2 = ta;
    u16* tb = b0; b0 = b1; b1 = b2; b2 = tb;
  }

  float bv[4];
#pragma unroll
  for (int n = 0; n < 4; ++n) bv[n] = bias[col0 + wn * 64 + n * 16 + fr];
#pragma unroll
  for (int m = 0; m < 8; ++m) {
#pragma unroll
    for (int j = 0; j < 4; ++j) {
      const long row = row0 + wm * 128 + m * 16 + g * 4 + j;
      const long base = row * N + col0 + wn * 64 + fr;
#pragma unroll
      for (int n = 0; n < 4; ++n) {
        float v = acc[m][n][j] + bv[n];
        if constexpr (EPI == 0) {
          ((u16*)outp)[base + n * 16] = f2bf(v);
        } else if constexpr (EPI == 1) {
          ((u16*)outp)[base + n * 16] = f2bf(gelu_f(v));
        } else {
          ((float*)outp)[base + n * 16] = v + res[base + n * 16];
        }
      }
    }
  }
}

// ---------------------------------------------------------------------------
// Relative position index (matches _rel_index in reference)
// ---------------------------------------------------------------------------
template<int LQ>
__device__ __forceinline__ int rel_index(int q, int k) {
  if constexpr (LQ == 64) {
    const int qh = q >> 3, qw = q & 7, kh = k >> 4, kw = k & 15;
    return (qh - kh + 15) * 23 + (qw - kw + 15);
  } else {
    const int qh = q >> 4, qw = q & 15, kh = k >> 3, kw = k & 7;
    return (qh - kh + 7) * 23 + (qw - kw + 7);
  }
}

// ---------------------------------------------------------------------------
// Fused cross attention, one block per (head, batch). 256 threads, MFMA.
// Q rows stride qs (q at offset 0); KV rows stride ks (k at +0, v at +768).
// ---------------------------------------------------------------------------
template<int LQ, int LK>
__global__ __launch_bounds__(256) void attn_kernel(
    const u16* __restrict__ Q, int qs, const u16* __restrict__ KV, int ks,
    const float* __restrict__ rpb, u16* __restrict__ O)
{
  constexpr int MT = LQ / 64;
  constexpr int NT = LK / 16;
  constexpr int KSPV = LK / 32;

  __shared__ __align__(16) u16 Qs[LQ * 64];
  __shared__ __align__(16) u16 Ks[LK * 64];
  __shared__ __align__(16) u16 Vt[64 * LK];
  __shared__ __align__(16) u16 Ps[LQ * LK];
  __shared__ float bias_s[529];

  const int h = blockIdx.x;
  const int b = blockIdx.y;
  const int tid = threadIdx.x;
  const int lane = tid & 63;
  const int w = tid >> 6;

  for (int i = tid; i < 529; i += 256) bias_s[i] = rpb[i * 12 + h];

#pragma unroll
  for (int it = 0; it < LQ * 8 / 256; ++it) {
    const int s = it * 256 + tid;
    const int r = s >> 3, sl2 = s & 7;
    bf16x8 v = *(const bf16x8*)&Q[(size_t)(b * LQ + r) * qs + h * 64 + sl2 * 8];
    *(bf16x8*)&Qs[r * 64 + ((sl2 ^ (r & 7)) * 8)] = v;
  }
#pragma unroll
  for (int it = 0; it < LK * 8 / 256; ++it) {
    const int s = it * 256 + tid;
    const int r = s >> 3, sl2 = s & 7;
    bf16x8 v = *(const bf16x8*)&KV[(size_t)(b * LK + r) * ks + h * 64 + sl2 * 8];
    *(bf16x8*)&Ks[r * 64 + ((sl2 ^ (r & 7)) * 8)] = v;
  }
#pragma unroll
  for (int it = 0; it < LK * 8 / 256; ++it) {
    const int s = it * 256 + tid;
    const int r = s >> 3, sl2 = s & 7;
    const int d0 = sl2 * 8;
    bf16x8 v = *(const bf16x8*)&KV[(size_t)(b * LK + r) * ks + 768 + h * 64 + d0];
#pragma unroll
    for (int j = 0; j < 8; ++j) {
      const int d = d0 + j;
      Vt[d * LK + (((r >> 3) ^ (d & 7)) * 8) + (r & 7)] = (u16)v[j];
    }
  }
  __syncthreads();

  const int fr = lane & 15;
  const int g = lane >> 4;
  const int qbase = w * MT * 16;

  f32x4 sacc[MT][NT];
#pragma unroll
  for (int mt = 0; mt < MT; ++mt)
#pragma unroll
    for (int nt = 0; nt < NT; ++nt) sacc[mt][nt] = (f32x4){0.f, 0.f, 0.f, 0.f};

#pragma unroll
  for (int mt = 0; mt < MT; ++mt) {
    const int qr = qbase + mt * 16 + fr;
    bf16x8 aq0 = *(const bf16x8*)&Qs[qr * 64 + (((0 + g) ^ (qr & 7)) * 8)];
    bf16x8 aq1 = *(const bf16x8*)&Qs[qr * 64 + (((4 + g) ^ (qr & 7)) * 8)];
#pragma unroll
    for (int nt = 0; nt < NT; ++nt) {
      const int kr = nt * 16 + fr;
      bf16x8 bk0 = *(const bf16x8*)&Ks[kr * 64 + (((0 + g) ^ (kr & 7)) * 8)];
      bf16x8 bk1 = *(const bf16x8*)&Ks[kr * 64 + (((4 + g) ^ (kr & 7)) * 8)];
      sacc[mt][nt] = __builtin_amdgcn_mfma_f32_16x16x32_bf16(aq0, bk0, sacc[mt][nt], 0, 0, 0);
      sacc[mt][nt] = __builtin_amdgcn_mfma_f32_16x16x32_bf16(aq1, bk1, sacc[mt][nt], 0, 0, 0);
    }
  }

#pragma unroll
  for (int mt = 0; mt < MT; ++mt) {
#pragma unroll
    for (int reg = 0; reg < 4; ++reg) {
      const int q = qbase + mt * 16 + g * 4 + reg;
      float mx = -3.0e38f;
#pragma unroll
      for (int nt = 0; nt < NT; ++nt) {
        const int k = nt * 16 + fr;
        float s = sacc[mt][nt][reg] * 0.125f + bias_s[rel_index<LQ>(q, k)];
        sacc[mt][nt][reg] = s;
        mx = fmaxf(mx, s);
      }
      mx = fmaxf(mx, __shfl_xor(mx, 1));
      mx = fmaxf(mx, __shfl_xor(mx, 2));
      mx = fmaxf(mx, __shfl_xor(mx, 4));
      mx = fmaxf(mx, __shfl_xor(mx, 8));
      float sum = 0.f;
#pragma unroll
      for (int nt = 0; nt < NT; ++nt) {
        float p = __expf(sacc[mt][nt][reg] - mx);
        sacc[mt][nt][reg] = p;
        sum += p;
      }
      sum += __shfl_xor(sum, 1);
      sum += __shfl_xor(sum, 2);
      sum += __shfl_xor(sum, 4);
      sum += __shfl_xor(sum, 8);
      const float inv = 1.0f / sum;
#pragma unroll
      for (int nt = 0; nt < NT; ++nt) {
        const int k = nt * 16 + fr;
        Ps[q * LK + (((k >> 3) ^ (q & 7)) * 8) + (k & 7)] = f2bf(sacc[mt][nt][reg] * inv);
      }
    }
  }
  __syncthreads();

  f32x4 oacc[MT][4];
#pragma unroll
  for (int mt = 0; mt < MT; ++mt)
#pragma unroll
    for (int n = 0; n < 4; ++n) oacc[mt][n] = (f32x4){0.f, 0.f, 0.f, 0.f};

#pragma unroll
  for (int mt = 0; mt < MT; ++mt) {
    const int pr = qbase + mt * 16 + fr;
#pragma unroll
    for (int ks2 = 0; ks2 < KSPV; ++ks2) {
      bf16x8 ap = *(const bf16x8*)&Ps[pr * LK + (((ks2 * 4 + g) ^ (pr & 7)) * 8)];
#pragma unroll
      for (int n = 0; n < 4; ++n) {
        const int d = n * 16 + fr;
        bf16x8 bvv = *(const bf16x8*)&Vt[d * LK + (((ks2 * 4 + g) ^ (d & 7)) * 8)];
        oacc[mt][n] = __builtin_amdgcn_mfma_f32_16x16x32_bf16(ap, bvv, oacc[mt][n], 0, 0, 0);
      }
    }
  }

#pragma unroll
  for (int mt = 0; mt < MT; ++mt)
#pragma unroll
    for (int n = 0; n < 4; ++n)
#pragma unroll
      for (int reg = 0; reg < 4; ++reg) {
        const int q = qbase + mt * 16 + g * 4 + reg;
        const int d = n * 16 + fr;
        O[(size_t)(b * LQ + q) * 768 + h * 64 + d] = f2bf(oacc[mt][n][reg]);
      }
}

// ---------------------------------------------------------------------------
// Host launcher
// ---------------------------------------------------------------------------
extern "C" void kernel_launch(void* const* d_in, const int* in_sizes, int n_in,
                              void* d_out, int out_size, void* d_ws, size_t ws_size,
                              hipStream_t stream)
{
  const float* z      = (const float*)d_in[0];
  const float* x      = (const float*)d_in[1];
  const float* zln1g  = (const float*)d_in[2];
  const float* zln1b  = (const float*)d_in[3];
  const float* xln1g  = (const float*)d_in[4];
  const float* xln1b  = (const float*)d_in[5];
  const float* zx_qw  = (const float*)d_in[6];
  const float* zx_qb  = (const float*)d_in[7];
  const float* zx_kvw = (const float*)d_in[8];
  const float* zx_kvb = (const float*)d_in[9];
  const float* zx_pw  = (const float*)d_in[10];
  const float* zx_pb  = (const float*)d_in[11];
  const float* zx_rpb = (const float*)d_in[12];
  const float* xz_qw  = (const float*)d_in[13];
  const float* xz_qb  = (const float*)d_in[14];
  const float* xz_kvw = (const float*)d_in[15];
  const float* xz_kvb = (const float*)d_in[16];
  const float* xz_pw  = (const float*)d_in[17];
  const float* xz_pb  = (const float*)d_in[18];
  const float* xz_rpb = (const float*)d_in[19];
  const float* zln2g  = (const float*)d_in[20];
  const float* zln2b  = (const float*)d_in[21];
  const float* zfc1w  = (const float*)d_in[22];
  const float* zfc1b  = (const float*)d_in[23];
  const float* zfc2w  = (const float*)d_in[24];
  const float* zfc2b  = (const float*)d_in[25];
  const float* xln2g  = (const float*)d_in[26];
  const float* xln2b  = (const float*)d_in[27];
  const float* xfc1w  = (const float*)d_in[28];
  const float* xfc1b  = (const float*)d_in[29];
  const float* xfc2w  = (const float*)d_in[30];
  const float* xfc2b  = (const float*)d_in[31];

  float* out = (float*)d_out;
  float* z2 = out;                       // 4096 x 768 f32
  float* x2 = out + 3145728;             // 16384 x 768 f32

  char* ws = (char*)d_ws;
  size_t off = 0;
  auto take = [&](size_t bytes) {
    char* p = ws + off;
    off += (bytes + 255) & ~(size_t)255;
    return p;
  };
  u16* w_zn   = (u16*)take(1769472 * 2);   // [zx_qw ; xz_kvw]  (2304 x 768)
  u16* w_xn   = (u16*)take(1769472 * 2);   // [xz_qw ; zx_kvw]
  u16* w_zx_p = (u16*)take(589824 * 2);
  u16* w_xz_p = (u16*)take(589824 * 2);
  u16* w_zfc1 = (u16*)take(2359296 * 2);
  u16* w_zfc2 = (u16*)take(2359296 * 2);
  u16* w_xfc1 = (u16*)take(2359296 * 2);
  u16* w_xfc2 = (u16*)take(2359296 * 2);
  float* b_zn = (float*)take(2304 * 4);
  float* b_xn = (float*)take(2304 * 4);
  u16* regA   = (u16*)take(31457280);      // zn|xn -> ao_z|ao_x -> z2n|x2n

  const size_t need_full = off + 100663296;
  const bool full = (ws_size >= need_full);
  u16* regB = (u16*)take(full ? 100663296 : 94371840);

  u16* zn    = regA;
  u16* xn    = regA + 3145728;
  u16* qkv_z = regB;                        // 4096 x 2304
  u16* qkv_x = regB + 9437184;              // 16384 x 2304
  u16* ao_z  = zn;
  u16* ao_x  = xn;
  u16* z2n   = zn;
  u16* x2n   = xn;
  u16* h     = regB;

  // 1. weights -> bf16 (packed qkv weights)
  Conv10 c;
  c.src[0] = zx_qw;  c.dst[0] = w_zn;           c.n[0] = 589824;
  c.src[1] = xz_kvw; c.dst[1] = w_zn + 589824;  c.n[1] = 1179648;
  c.src[2] = xz_qw;  c.dst[2] = w_xn;           c.n[2] = 589824;
  c.src[3] = zx_kvw; c.dst[3] = w_xn + 589824;  c.n[3] = 1179648;
  c.src[4] = zx_pw;  c.dst[4] = w_zx_p;         c.n[4] = 589824;
  c.src[5] = xz_pw;  c.dst[5] = w_xz_p;         c.n[5] = 589824;
  c.src[6] = zfc1w;  c.dst[6] = w_zfc1;         c.n[6] = 2359296;
  c.src[7] = zfc2w;  c.dst[7] = w_zfc2;         c.n[7] = 2359296;
  c.src[8] = xfc1w;  c.dst[8] = w_xfc1;         c.n[8] = 2359296;
  c.src[9] = xfc2w;  c.dst[9] = w_xfc2;         c.n[9] = 2359296;
  convert10<<<dim3(2304, 10), 256, 0, stream>>>(c);
  pack_bias<<<9, 256, 0, stream>>>(zx_qb, xz_kvb, xz_qb, zx_kvb, b_zn, b_xn);

  // 2. LN1
  ln_dual<<<5120, 256, 0, stream>>>(z, zln1g, zln1b, zn, 4096, x, xln1g, xln1b, xn);

  // 3. packed QKV projections: zn -> [q_z | kv_z], xn -> [q_x | kv_x]
  gemm_bt<0><<<dim3(18, 32), 256, 0, stream>>>(zn, w_zn, b_zn, nullptr, qkv_z, 4096, 2304, 768);
  gemm5<0><<<dim3(18, 64), 256, 0, stream>>>(xn, w_xn, b_xn, nullptr, qkv_x, 16384, 2304, 768);

  // 4. attention: z-attn uses q from qkv_z, kv from qkv_x (+768); x-attn vice versa
  attn_kernel<64, 256><<<dim3(12, 64), 256, 0, stream>>>(qkv_z, 2304, qkv_x + 768, 2304, zx_rpb, ao_z);
  attn_kernel<256, 64><<<dim3(12, 64), 256, 0, stream>>>(qkv_x, 2304, qkv_z + 768, 2304, xz_rpb, ao_x);

  // 5. output proj + residual
  gemm_bt<2><<<dim3(6, 32), 256, 0, stream>>>(ao_z, w_zx_p, zx_pb, z, z2, 4096, 768, 768);
  gemm5<2><<<dim3(6, 64), 256, 0, stream>>>(ao_x, w_xz_p, xz_pb, x, x2, 16384, 768, 768);

  // 6. LN2
  ln_dual<<<5120, 256, 0, stream>>>(z2, zln2g, zln2b, z2n, 4096, x2, xln2g, xln2b, x2n);

  // 7. MLPs
  gemm5<1><<<dim3(24, 16), 256, 0, stream>>>(z2n, w_zfc1, zfc1b, nullptr, h, 4096, 3072, 768);
  gemm_bt<2><<<dim3(6, 32), 256, 0, stream>>>(h, w_zfc2, zfc2b, z2, z2, 4096, 768, 3072);

  if (full) {
    gemm5<1><<<dim3(24, 64), 256, 0, stream>>>(x2n, w_xfc1, xfc1b, nullptr, h, 16384, 3072, 768);
    gemm5<2><<<dim3(6, 64),  256, 0, stream>>>(h, w_xfc2, xfc2b, x2, x2, 16384, 768, 3072);
  } else {
    gemm5<1><<<dim3(24, 32), 256, 0, stream>>>(x2n, w_xfc1, xfc1b, nullptr, h, 8192, 3072, 768);
    gemm5<2><<<dim3(6, 32),  256, 0, stream>>>(h, w_xfc2, xfc2b, x2, x2, 8192, 768, 3072);
    gemm5<1><<<dim3(24, 32), 256, 0, stream>>>(x2n + (size_t)8192 * 768, w_xfc1, xfc1b, nullptr, h, 8192, 3072, 768);
    gemm5<2><<<dim3(6, 32),  256, 0, stream>>>(h, w_xfc2, xfc2b, x2 + (size_t)8192 * 768, x2 + (size_t)8192 * 768, 8192, 768, 3072);
  }
}

// Round 8
// 569.717 us; speedup vs baseline: 1.5500x; 1.2296x over previous
//
#include <hip/hip_runtime.h>
#include <math.h>

typedef unsigned short u16;
typedef unsigned int u32;
typedef __attribute__((ext_vector_type(8))) short bf16x8;
typedef __attribute__((ext_vector_type(4))) float f32x4;
typedef __attribute__((ext_vector_type(4))) u16 u16x4;

__device__ __forceinline__ u16 f2bf(float f) {
  u32 u = __builtin_bit_cast(u32, f);
  u32 r = (u + 0x7fffu + ((u >> 16) & 1u)) >> 16;
  return (u16)r;
}

// fast gelu: v*sigmoid(1.5957691*v*(1+0.044715*v^2)); |err|<3e-3 << 0.1175 thr
__device__ __forceinline__ float gelu_f(float v) {
  float u = 1.5957691216057308f * v * (1.0f + 0.044715f * v * v);
  return v / (1.0f + __expf(-u));
}

__device__ __forceinline__ void async16(const void* g, void* l) {
  __builtin_amdgcn_global_load_lds(
      (__attribute__((address_space(1))) void*)(unsigned long long)(const char*)g,
      (__attribute__((address_space(3))) void*)l, 16, 0, 0);
}

#define SCHED0 __builtin_amdgcn_sched_barrier(0)
#define BARRIER __builtin_amdgcn_s_barrier()

// ---------------------------------------------------------------------------
// Weight f32 -> bf16 conversion (10 segments, one launch)
// ---------------------------------------------------------------------------
struct Conv10 {
  const float* src[10];
  u16* dst[10];
  int n[10];
};

__global__ __launch_bounds__(256) void convert10(Conv10 a) {
  const int seg = blockIdx.y;
  const long i = ((long)blockIdx.x * 256 + threadIdx.x) * 4;
  if (i >= a.n[seg]) return;
  float4 v = *(const float4*)&a.src[seg][i];
  u16x4 o;
  o.x = f2bf(v.x); o.y = f2bf(v.y); o.z = f2bf(v.z); o.w = f2bf(v.w);
  *(u16x4*)&a.dst[seg][i] = o;
}

// pack two 2304-col bias vectors from 4 inputs
__global__ __launch_bounds__(256) void pack_bias(
    const float* __restrict__ zq, const float* __restrict__ zkv,
    const float* __restrict__ xq, const float* __restrict__ xkv,
    float* __restrict__ bz, float* __restrict__ bx)
{
  const int i = blockIdx.x * 256 + threadIdx.x;
  if (i >= 2304) return;
  bz[i] = (i < 768) ? zq[i] : zkv[i - 768];
  bx[i] = (i < 768) ? xq[i] : xkv[i - 768];
}

// ---------------------------------------------------------------------------
// LayerNorm (two tensors fused in one launch), f32 in -> bf16 out, 1 wave/row
// ---------------------------------------------------------------------------
__global__ __launch_bounds__(256) void ln_dual(
    const float* __restrict__ in1, const float* __restrict__ g1, const float* __restrict__ b1,
    u16* __restrict__ out1, int rows1,
    const float* __restrict__ in2, const float* __restrict__ g2, const float* __restrict__ b2,
    u16* __restrict__ out2)
{
  const int w = threadIdx.x >> 6;
  const int lane = threadIdx.x & 63;
  const int row = blockIdx.x * 4 + w;
  const float* in; const float* gg; const float* bb; u16* out;
  if (row < rows1) { in = in1 + (size_t)row * 768; gg = g1; bb = b1; out = out1 + (size_t)row * 768; }
  else { const int r2 = row - rows1; in = in2 + (size_t)r2 * 768; gg = g2; bb = b2; out = out2 + (size_t)r2 * 768; }

  float4 v0 = *(const float4*)&in[lane * 4];
  float4 v1 = *(const float4*)&in[lane * 4 + 256];
  float4 v2 = *(const float4*)&in[lane * 4 + 512];
  float s = v0.x + v0.y + v0.z + v0.w + v1.x + v1.y + v1.z + v1.w + v2.x + v2.y + v2.z + v2.w;
  float s2 = v0.x*v0.x + v0.y*v0.y + v0.z*v0.z + v0.w*v0.w
           + v1.x*v1.x + v1.y*v1.y + v1.z*v1.z + v1.w*v1.w
           + v2.x*v2.x + v2.y*v2.y + v2.z*v2.z + v2.w*v2.w;
#pragma unroll
  for (int m = 1; m <= 32; m <<= 1) { s += __shfl_xor(s, m); s2 += __shfl_xor(s2, m); }
  const float mean = s * (1.0f / 768.0f);
  const float var = s2 * (1.0f / 768.0f) - mean * mean;
  const float rs = rsqrtf(var + 1e-5f);

#define LNSTORE(V, OFFS) { \
    float4 gv = *(const float4*)&gg[lane * 4 + OFFS]; \
    float4 bv = *(const float4*)&bb[lane * 4 + OFFS]; \
    u16x4 o; \
    o.x = f2bf((V.x - mean) * rs * gv.x + bv.x); \
    o.y = f2bf((V.y - mean) * rs * gv.y + bv.y); \
    o.z = f2bf((V.z - mean) * rs * gv.z + bv.z); \
    o.w = f2bf((V.w - mean) * rs * gv.w + bv.w); \
    *(u16x4*)&out[lane * 4 + OFFS] = o; }
  LNSTORE(v0, 0)
  LNSTORE(v1, 256)
  LNSTORE(v2, 512)
#undef LNSTORE
}

// ---------------------------------------------------------------------------
// gemm5 core: 256x128 tile, BK=32, 4 waves, per-wave 128x64 output.
// 3 LDS buffers, prefetch depth 2, counted waits (vmcnt(6)+lgkmcnt(0)),
// setprio around MFMA cluster. Swizzle slot ^ ((row>>1)&3) pre-applied on
// global source, linear gload_lds dest, matching read XOR (2-way = free).
// gemm5f: fused z+x variant — by < Y0 routes to pointer-set 0 (z), else 1.
// ---------------------------------------------------------------------------
template<int EPI>
__device__ __forceinline__ void gemm5_core(
    const u16* __restrict__ A, const u16* __restrict__ W,
    const float* __restrict__ bias, const float* __restrict__ res,
    void* __restrict__ outp, long row0, long col0, int N, int K)
{
  __shared__ __align__(16) u16 As[3][256 * 32];
  __shared__ __align__(16) u16 Bs[3][128 * 32];

  const int tid = threadIdx.x;
  const int lane = tid & 63;
  const int w = tid >> 6;
  const int wm = w >> 1;
  const int wn = w & 1;

  const u16* gA[4];
  const u16* gB[2];
#pragma unroll
  for (int l = 0; l < 4; ++l) {
    const int e = l * 256 + tid;
    const int r = e >> 2, sl = e & 3;
    gA[l] = A + (row0 + r) * (long)K + ((sl ^ ((r >> 1) & 3)) * 8);
  }
#pragma unroll
  for (int l = 0; l < 2; ++l) {
    const int e = l * 256 + tid;
    const int r = e >> 2, sl = e & 3;
    gB[l] = W + (col0 + r) * (long)K + ((sl ^ ((r >> 1) & 3)) * 8);
  }

  const int fr = lane & 15;
  const int g = lane >> 4;

  f32x4 acc[8][4];
#pragma unroll
  for (int m = 0; m < 8; ++m)
#pragma unroll
    for (int n = 0; n < 4; ++n) acc[m][n] = (f32x4){0.f, 0.f, 0.f, 0.f};

  auto stage = [&](u16* ab, u16* bb, long ko) {
#pragma unroll
    for (int l = 0; l < 4; ++l) async16(gA[l] + ko, &ab[(l * 256 + tid) * 8]);
#pragma unroll
    for (int l = 0; l < 2; ++l) async16(gB[l] + ko, &bb[(l * 256 + tid) * 8]);
  };

  const int nt = K / 32;
  u16 *a0 = &As[0][0], *a1 = &As[1][0], *a2 = &As[2][0];
  u16 *b0 = &Bs[0][0], *b1 = &Bs[1][0], *b2 = &Bs[2][0];

  stage(a0, b0, 0);
  stage(a1, b1, 32);
  SCHED0;
  asm volatile("s_waitcnt vmcnt(6)" ::: "memory");
  BARRIER;
  SCHED0;

  for (int t = 0; t < nt; ++t) {
    if (t + 2 < nt) stage(a2, b2, (long)(t + 2) * 32);
    SCHED0;
    bf16x8 bfr[4];
#pragma unroll
    for (int n = 0; n < 4; ++n) {
      const int r = wn * 64 + n * 16 + fr;
      bfr[n] = *(const bf16x8*)&b0[r * 32 + ((g ^ ((r >> 1) & 3)) * 8)];
    }
    __builtin_amdgcn_s_setprio(1);
#pragma unroll
    for (int m = 0; m < 8; ++m) {
      const int r = wm * 128 + m * 16 + fr;
      bf16x8 af = *(const bf16x8*)&a0[r * 32 + ((g ^ ((r >> 1) & 3)) * 8)];
#pragma unroll
      for (int n = 0; n < 4; ++n)
        acc[m][n] = __builtin_amdgcn_mfma_f32_16x16x32_bf16(af, bfr[n], acc[m][n], 0, 0, 0);
    }
    __builtin_amdgcn_s_setprio(0);
    SCHED0;
    if (t + 2 < nt) {
      asm volatile("s_waitcnt vmcnt(6) lgkmcnt(0)" ::: "memory");
    } else if (t + 1 < nt) {
      asm volatile("s_waitcnt vmcnt(0) lgkmcnt(0)" ::: "memory");
    }
    if (t + 1 < nt) { BARRIER; SCHED0; }
    u16* ta = a0; a0 = a1; a1 = a2; a2 = ta;
    u16* tb = b0; b0 = b1; b1 = b2; b2 = tb;
  }

  float bv[4];
#pragma unroll
  for (int n = 0; n < 4; ++n) bv[n] = bias[col0 + wn * 64 + n * 16 + fr];
#pragma unroll
  for (int m = 0; m < 8; ++m) {
#pragma unroll
    for (int j = 0; j < 4; ++j) {
      const long row = row0 + wm * 128 + m * 16 + g * 4 + j;
      const long base = row * N + col0 + wn * 64 + fr;
#pragma unroll
      for (int n = 0; n < 4; ++n) {
        float v = acc[m][n][j] + bv[n];
        if constexpr (EPI == 0) {
          ((u16*)outp)[base + n * 16] = f2bf(v);
        } else if constexpr (EPI == 1) {
          ((u16*)outp)[base + n * 16] = f2bf(gelu_f(v));
        } else {
          ((float*)outp)[base + n * 16] = v + res[base + n * 16];
        }
      }
    }
  }
}

template<int EPI>
__global__ __launch_bounds__(256, 2) void gemm5(
    const u16* __restrict__ A, const u16* __restrict__ W,
    const float* __restrict__ bias, const float* __restrict__ res,
    void* __restrict__ outp, int M, int N, int K)
{
  int flat = blockIdx.y * gridDim.x + blockIdx.x;
  const int nwg = gridDim.x * gridDim.y;
  if ((nwg & 7) == 0) flat = (flat & 7) * (nwg >> 3) + (flat >> 3);
  const int bx = flat % gridDim.x;
  const int by = flat / gridDim.x;
  gemm5_core<EPI>(A, W, bias, res, outp, (long)by * 256, (long)bx * 128, N, K);
}

// fused z+x: pointer-set 0 for by < Y0, set 1 otherwise (shared or distinct W)
template<int EPI>
__global__ __launch_bounds__(256, 2) void gemm5f(
    const u16* __restrict__ A0, const u16* __restrict__ W0,
    const float* __restrict__ bias0, const float* __restrict__ res0, void* __restrict__ out0,
    const u16* __restrict__ A1, const u16* __restrict__ W1,
    const float* __restrict__ bias1, const float* __restrict__ res1, void* __restrict__ out1,
    int Y0, int N, int K)
{
  int flat = blockIdx.y * gridDim.x + blockIdx.x;
  const int nwg = gridDim.x * gridDim.y;
  if ((nwg & 7) == 0) flat = (flat & 7) * (nwg >> 3) + (flat >> 3);
  const int bx = flat % gridDim.x;
  const int by = flat / gridDim.x;
  if (by < Y0) {
    gemm5_core<EPI>(A0, W0, bias0, res0, out0, (long)by * 256, (long)bx * 128, N, K);
  } else {
    gemm5_core<EPI>(A1, W1, bias1, res1, out1, (long)(by - Y0) * 256, (long)bx * 128, N, K);
  }
}

// ---------------------------------------------------------------------------
// Relative position index (matches _rel_index in reference)
// ---------------------------------------------------------------------------
template<int LQ>
__device__ __forceinline__ int rel_index(int q, int k) {
  if constexpr (LQ == 64) {
    const int qh = q >> 3, qw = q & 7, kh = k >> 4, kw = k & 15;
    return (qh - kh + 15) * 23 + (qw - kw + 15);
  } else {
    const int qh = q >> 4, qw = q & 15, kh = k >> 3, kw = k & 7;
    return (qh - kh + 7) * 23 + (qw - kw + 7);
  }
}

// ---------------------------------------------------------------------------
// Fused cross attention, one block per (head, batch). 256 threads, MFMA.
// Q rows stride qs (q at offset 0); KV rows stride ks (k at +0, v at +768).
// ---------------------------------------------------------------------------
template<int LQ, int LK>
__global__ __launch_bounds__(256) void attn_kernel(
    const u16* __restrict__ Q, int qs, const u16* __restrict__ KV, int ks,
    const float* __restrict__ rpb, u16* __restrict__ O)
{
  constexpr int MT = LQ / 64;
  constexpr int NT = LK / 16;
  constexpr int KSPV = LK / 32;

  __shared__ __align__(16) u16 Qs[LQ * 64];
  __shared__ __align__(16) u16 Ks[LK * 64];
  __shared__ __align__(16) u16 Vt[64 * LK];
  __shared__ __align__(16) u16 Ps[LQ * LK];
  __shared__ float bias_s[529];

  const int h = blockIdx.x;
  const int b = blockIdx.y;
  const int tid = threadIdx.x;
  const int lane = tid & 63;
  const int w = tid >> 6;

  for (int i = tid; i < 529; i += 256) bias_s[i] = rpb[i * 12 + h];

#pragma unroll
  for (int it = 0; it < LQ * 8 / 256; ++it) {
    const int s = it * 256 + tid;
    const int r = s >> 3, sl2 = s & 7;
    bf16x8 v = *(const bf16x8*)&Q[(size_t)(b * LQ + r) * qs + h * 64 + sl2 * 8];
    *(bf16x8*)&Qs[r * 64 + ((sl2 ^ (r & 7)) * 8)] = v;
  }
#pragma unroll
  for (int it = 0; it < LK * 8 / 256; ++it) {
    const int s = it * 256 + tid;
    const int r = s >> 3, sl2 = s & 7;
    bf16x8 v = *(const bf16x8*)&KV[(size_t)(b * LK + r) * ks + h * 64 + sl2 * 8];
    *(bf16x8*)&Ks[r * 64 + ((sl2 ^ (r & 7)) * 8)] = v;
  }
#pragma unroll
  for (int it = 0; it < LK * 8 / 256; ++it) {
    const int s = it * 256 + tid;
    const int r = s >> 3, sl2 = s & 7;
    const int d0 = sl2 * 8;
    bf16x8 v = *(const bf16x8*)&KV[(size_t)(b * LK + r) * ks + 768 + h * 64 + d0];
#pragma unroll
    for (int j = 0; j < 8; ++j) {
      const int d = d0 + j;
      Vt[d * LK + (((r >> 3) ^ (d & 7)) * 8) + (r & 7)] = (u16)v[j];
    }
  }
  __syncthreads();

  const int fr = lane & 15;
  const int g = lane >> 4;
  const int qbase = w * MT * 16;

  f32x4 sacc[MT][NT];
#pragma unroll
  for (int mt = 0; mt < MT; ++mt)
#pragma unroll
    for (int nt = 0; nt < NT; ++nt) sacc[mt][nt] = (f32x4){0.f, 0.f, 0.f, 0.f};

#pragma unroll
  for (int mt = 0; mt < MT; ++mt) {
    const int qr = qbase + mt * 16 + fr;
    bf16x8 aq0 = *(const bf16x8*)&Qs[qr * 64 + (((0 + g) ^ (qr & 7)) * 8)];
    bf16x8 aq1 = *(const bf16x8*)&Qs[qr * 64 + (((4 + g) ^ (qr & 7)) * 8)];
#pragma unroll
    for (int nt = 0; nt < NT; ++nt) {
      const int kr = nt * 16 + fr;
      bf16x8 bk0 = *(const bf16x8*)&Ks[kr * 64 + (((0 + g) ^ (kr & 7)) * 8)];
      bf16x8 bk1 = *(const bf16x8*)&Ks[kr * 64 + (((4 + g) ^ (kr & 7)) * 8)];
      sacc[mt][nt] = __builtin_amdgcn_mfma_f32_16x16x32_bf16(aq0, bk0, sacc[mt][nt], 0, 0, 0);
      sacc[mt][nt] = __builtin_amdgcn_mfma_f32_16x16x32_bf16(aq1, bk1, sacc[mt][nt], 0, 0, 0);
    }
  }

#pragma unroll
  for (int mt = 0; mt < MT; ++mt) {
#pragma unroll
    for (int reg = 0; reg < 4; ++reg) {
      const int q = qbase + mt * 16 + g * 4 + reg;
      float mx = -3.0e38f;
#pragma unroll
      for (int nt = 0; nt < NT; ++nt) {
        const int k = nt * 16 + fr;
        float s = sacc[mt][nt][reg] * 0.125f + bias_s[rel_index<LQ>(q, k)];
        sacc[mt][nt][reg] = s;
        mx = fmaxf(mx, s);
      }
      mx = fmaxf(mx, __shfl_xor(mx, 1));
      mx = fmaxf(mx, __shfl_xor(mx, 2));
      mx = fmaxf(mx, __shfl_xor(mx, 4));
      mx = fmaxf(mx, __shfl_xor(mx, 8));
      float sum = 0.f;
#pragma unroll
      for (int nt = 0; nt < NT; ++nt) {
        float p = __expf(sacc[mt][nt][reg] - mx);
        sacc[mt][nt][reg] = p;
        sum += p;
      }
      sum += __shfl_xor(sum, 1);
      sum += __shfl_xor(sum, 2);
      sum += __shfl_xor(sum, 4);
      sum += __shfl_xor(sum, 8);
      const float inv = 1.0f / sum;
#pragma unroll
      for (int nt = 0; nt < NT; ++nt) {
        const int k = nt * 16 + fr;
        Ps[q * LK + (((k >> 3) ^ (q & 7)) * 8) + (k & 7)] = f2bf(sacc[mt][nt][reg] * inv);
      }
    }
  }
  __syncthreads();

  f32x4 oacc[MT][4];
#pragma unroll
  for (int mt = 0; mt < MT; ++mt)
#pragma unroll
    for (int n = 0; n < 4; ++n) oacc[mt][n] = (f32x4){0.f, 0.f, 0.f, 0.f};

#pragma unroll
  for (int mt = 0; mt < MT; ++mt) {
    const int pr = qbase + mt * 16 + fr;
#pragma unroll
    for (int ks2 = 0; ks2 < KSPV; ++ks2) {
      bf16x8 ap = *(const bf16x8*)&Ps[pr * LK + (((ks2 * 4 + g) ^ (pr & 7)) * 8)];
#pragma unroll
      for (int n = 0; n < 4; ++n) {
        const int d = n * 16 + fr;
        bf16x8 bvv = *(const bf16x8*)&Vt[d * LK + (((ks2 * 4 + g) ^ (d & 7)) * 8)];
        oacc[mt][n] = __builtin_amdgcn_mfma_f32_16x16x32_bf16(ap, bvv, oacc[mt][n], 0, 0, 0);
      }
    }
  }

#pragma unroll
  for (int mt = 0; mt < MT; ++mt)
#pragma unroll
    for (int n = 0; n < 4; ++n)
#pragma unroll
      for (int reg = 0; reg < 4; ++reg) {
        const int q = qbase + mt * 16 + g * 4 + reg;
        const int d = n * 16 + fr;
        O[(size_t)(b * LQ + q) * 768 + h * 64 + d] = f2bf(oacc[mt][n][reg]);
      }
}

// ---------------------------------------------------------------------------
// Host launcher
// ---------------------------------------------------------------------------
extern "C" void kernel_launch(void* const* d_in, const int* in_sizes, int n_in,
                              void* d_out, int out_size, void* d_ws, size_t ws_size,
                              hipStream_t stream)
{
  const float* z      = (const float*)d_in[0];
  const float* x      = (const float*)d_in[1];
  const float* zln1g  = (const float*)d_in[2];
  const float* zln1b  = (const float*)d_in[3];
  const float* xln1g  = (const float*)d_in[4];
  const float* xln1b  = (const float*)d_in[5];
  const float* zx_qw  = (const float*)d_in[6];
  const float* zx_qb  = (const float*)d_in[7];
  const float* zx_kvw = (const float*)d_in[8];
  const float* zx_kvb = (const float*)d_in[9];
  const float* zx_pw  = (const float*)d_in[10];
  const float* zx_pb  = (const float*)d_in[11];
  const float* zx_rpb = (const float*)d_in[12];
  const float* xz_qw  = (const float*)d_in[13];
  const float* xz_qb  = (const float*)d_in[14];
  const float* xz_kvw = (const float*)d_in[15];
  const float* xz_kvb = (const float*)d_in[16];
  const float* xz_pw  = (const float*)d_in[17];
  const float* xz_pb  = (const float*)d_in[18];
  const float* xz_rpb = (const float*)d_in[19];
  const float* zln2g  = (const float*)d_in[20];
  const float* zln2b  = (const float*)d_in[21];
  const float* zfc1w  = (const float*)d_in[22];
  const float* zfc1b  = (const float*)d_in[23];
  const float* zfc2w  = (const float*)d_in[24];
  const float* zfc2b  = (const float*)d_in[25];
  const float* xln2g  = (const float*)d_in[26];
  const float* xln2b  = (const float*)d_in[27];
  const float* xfc1w  = (const float*)d_in[28];
  const float* xfc1b  = (const float*)d_in[29];
  const float* xfc2w  = (const float*)d_in[30];
  const float* xfc2b  = (const float*)d_in[31];

  float* out = (float*)d_out;
  float* z2 = out;                       // 4096 x 768 f32
  float* x2 = out + 3145728;             // 16384 x 768 f32

  char* ws = (char*)d_ws;
  size_t off = 0;
  auto take = [&](size_t bytes) {
    char* p = ws + off;
    off += (bytes + 255) & ~(size_t)255;
    return p;
  };
  u16* w_zn   = (u16*)take(1769472 * 2);   // [zx_qw ; xz_kvw]  (2304 x 768)
  u16* w_xn   = (u16*)take(1769472 * 2);   // [xz_qw ; zx_kvw]
  u16* w_zx_p = (u16*)take(589824 * 2);
  u16* w_xz_p = (u16*)take(589824 * 2);
  u16* w_zfc1 = (u16*)take(2359296 * 2);
  u16* w_zfc2 = (u16*)take(2359296 * 2);
  u16* w_xfc1 = (u16*)take(2359296 * 2);
  u16* w_xfc2 = (u16*)take(2359296 * 2);
  float* b_zn = (float*)take(2304 * 4);
  float* b_xn = (float*)take(2304 * 4);
  u16* regA   = (u16*)take(31457280);      // zn|xn -> ao_z|ao_x -> z2n|x2n

  // regB: qkv (94.4 MB) reused as hz+hx (full: 125.8 MB, else hz+hx_half 75.5)
  const size_t need_full = off + 125829120;
  const bool full = (ws_size >= need_full);
  u16* regB = (u16*)take(full ? 125829120 : 94371840);

  u16* zn    = regA;
  u16* xn    = regA + 3145728;
  u16* qkv_z = regB;                        // 4096 x 2304
  u16* qkv_x = regB + 9437184;              // 16384 x 2304
  u16* ao_z  = zn;
  u16* ao_x  = xn;
  u16* z2n   = zn;
  u16* x2n   = xn;
  u16* hz    = regB;                        // 4096 x 3072
  u16* hx    = regB + 12582912;             // 16384 (or 8192) x 3072

  // 1. weights -> bf16 (packed qkv weights)
  Conv10 c;
  c.src[0] = zx_qw;  c.dst[0] = w_zn;           c.n[0] = 589824;
  c.src[1] = xz_kvw; c.dst[1] = w_zn + 589824;  c.n[1] = 1179648;
  c.src[2] = xz_qw;  c.dst[2] = w_xn;           c.n[2] = 589824;
  c.src[3] = zx_kvw; c.dst[3] = w_xn + 589824;  c.n[3] = 1179648;
  c.src[4] = zx_pw;  c.dst[4] = w_zx_p;         c.n[4] = 589824;
  c.src[5] = xz_pw;  c.dst[5] = w_xz_p;         c.n[5] = 589824;
  c.src[6] = zfc1w;  c.dst[6] = w_zfc1;         c.n[6] = 2359296;
  c.src[7] = zfc2w;  c.dst[7] = w_zfc2;         c.n[7] = 2359296;
  c.src[8] = xfc1w;  c.dst[8] = w_xfc1;         c.n[8] = 2359296;
  c.src[9] = xfc2w;  c.dst[9] = w_xfc2;         c.n[9] = 2359296;
  convert10<<<dim3(2304, 10), 256, 0, stream>>>(c);
  pack_bias<<<9, 256, 0, stream>>>(zx_qb, xz_kvb, xz_qb, zx_kvb, b_zn, b_xn);

  // 2. LN1
  ln_dual<<<5120, 256, 0, stream>>>(z, zln1g, zln1b, zn, 4096, x, xln1g, xln1b, xn);

  // 3. fused packed QKV: zn -> [q_z|kv_z], xn -> [q_x|kv_x]  (grid 18 x 80)
  gemm5f<0><<<dim3(18, 80), 256, 0, stream>>>(
      zn, w_zn, b_zn, nullptr, qkv_z,
      xn, w_xn, b_xn, nullptr, qkv_x, 16, 2304, 768);

  // 4. attention
  attn_kernel<64, 256><<<dim3(12, 64), 256, 0, stream>>>(qkv_z, 2304, qkv_x + 768, 2304, zx_rpb, ao_z);
  attn_kernel<256, 64><<<dim3(12, 64), 256, 0, stream>>>(qkv_x, 2304, qkv_z + 768, 2304, xz_rpb, ao_x);

  // 5. fused output proj + residual (grid 6 x 80)
  gemm5f<2><<<dim3(6, 80), 256, 0, stream>>>(
      ao_z, w_zx_p, zx_pb, z, z2,
      ao_x, w_xz_p, xz_pb, x, x2, 16, 768, 768);

  // 6. LN2
  ln_dual<<<5120, 256, 0, stream>>>(z2, zln2g, zln2b, z2n, 4096, x2, xln2g, xln2b, x2n);

  // 7. fused MLPs
  if (full) {
    gemm5f<1><<<dim3(24, 80), 256, 0, stream>>>(
        z2n, w_zfc1, zfc1b, nullptr, hz,
        x2n, w_xfc1, xfc1b, nullptr, hx, 16, 3072, 768);
    gemm5f<2><<<dim3(6, 80), 256, 0, stream>>>(
        hz, w_zfc2, zfc2b, z2, z2,
        hx, w_xfc2, xfc2b, x2, x2, 16, 768, 3072);
  } else {
    // half-x fused, then remaining x half standalone
    gemm5f<1><<<dim3(24, 48), 256, 0, stream>>>(
        z2n, w_zfc1, zfc1b, nullptr, hz,
        x2n, w_xfc1, xfc1b, nullptr, hx, 16, 3072, 768);
    gemm5f<2><<<dim3(6, 48), 256, 0, stream>>>(
        hz, w_zfc2, zfc2b, z2, z2,
        hx, w_xfc2, xfc2b, x2, x2, 16, 768, 3072);
    gemm5<1><<<dim3(24, 32), 256, 0, stream>>>(x2n + (size_t)8192 * 768, w_xfc1, xfc1b, nullptr, hx, 8192, 3072, 768);
    gemm5<2><<<dim3(6, 32),  256, 0, stream>>>(hx, w_xfc2, xfc2b, x2 + (size_t)8192 * 768, x2 + (size_t)8192 * 768, 8192, 768, 3072);
  }
}